// Round 15
// baseline (231.977 us; speedup 1.0000x reference)
//
#include <hip/hip_runtime.h>
#include <hip/hip_bf16.h>
#include <stdint.h>
#include <stddef.h>

#define HW 262144          // 512*512
#define EPSF 1e-5f

typedef __hip_bfloat16 bf16;

__device__ __forceinline__ float us2f(uint32_t u){
  union { uint32_t i; float f; } c; c.i = u << 16; return c.f;
}
__device__ __forceinline__ ushort f2bu(float v){
  union { bf16 h; ushort u; } c; c.h = __float2bfloat16(v); return c.u;
}
__device__ __forceinline__ float lrelu(float v){ return v > 0.0f ? v : 0.01f * v; }
__device__ __forceinline__ uint32_t umax2(uint32_t a, uint32_t b){ return a > b ? a : b; }

// ---------------------------------------------------------------------------
// K0: 11x11 mode filter with FUSED quantize+reflect-pad staging (vectorized).
// ---------------------------------------------------------------------------
__global__ __launch_bounds__(256) void k_mode(const float* __restrict__ x,
                                              uint8_t* __restrict__ xm){
  __shared__ uint8_t tile[14 * 528];
  int tid = threadIdx.x;
  int img = blockIdx.x >> 7;
  int h0  = (blockIdx.x & 127) << 2;          // first output row of block
  {
    const float* xp = x + img * HW;
    // interior: 14 rows x 128 dwords (ws = 4*g), one u32 store each
    #pragma unroll 1
    for (int idx = tid; idx < 14 * 128; idx += 256){
      int r = idx >> 7, g = idx & 127;
      int hs = h0 + r - 5; hs = hs < 0 ? -hs : hs; if (hs > 511) hs = 1022 - hs;
      int ws = g << 2;
      float4 v = *(const float4*)(xp + hs * 512 + ws);
      uint32_t b0 = (uint32_t)(uint8_t)(int)rintf((v.x * 255.0f) / 16.0f);
      uint32_t b1 = (uint32_t)(uint8_t)(int)rintf((v.y * 255.0f) / 16.0f);
      uint32_t b2 = (uint32_t)(uint8_t)(int)rintf((v.z * 255.0f) / 16.0f);
      uint32_t b3 = (uint32_t)(uint8_t)(int)rintf((v.w * 255.0f) / 16.0f);
      *(uint32_t*)&tile[r * 528 + 8 + ws] = b0 | (b1 << 8) | (b2 << 16) | (b3 << 24);
    }
    // halo: 14 rows x 10 cols (pw 0..4 and 517..521), scalar bytes
    if (tid < 140){
      int r = tid / 10, i = tid % 10;
      int pw = (i < 5) ? i : (512 + i);      // 0..4 or 517..521
      int hs = h0 + r - 5; hs = hs < 0 ? -hs : hs; if (hs > 511) hs = 1022 - hs;
      int ws = pw - 5; ws = ws < 0 ? -ws : ws; if (ws > 511) ws = 1022 - ws;
      float v = xp[hs * 512 + ws];
      tile[r * 528 + 3 + pw] = (uint8_t)(int)rintf((v * 255.0f) / 16.0f);
    }
  }
  __syncthreads();
  int r4 = tid >> 6;                          // row within block 0..3
  int w0 = (tid & 63) << 3;                   // 0..504
  const uint8_t* base = tile + r4 * 528 + 3 + w0;
  uint32_t c0 = 0, c1 = 0, c2 = 0, c3 = 0, c4 = 0;
#define HINC(q) { uint32_t inc_ = 1u << (((q) & 3u) << 3); uint32_t rr_ = (q) >> 2; \
    c0 += (rr_==0u)?inc_:0u; c1 += (rr_==1u)?inc_:0u; c2 += (rr_==2u)?inc_:0u; \
    c3 += (rr_==3u)?inc_:0u; c4 += (rr_==4u)?inc_:0u; }
#define HDEC(q) { uint32_t inc_ = 1u << (((q) & 3u) << 3); uint32_t rr_ = (q) >> 2; \
    c0 -= (rr_==0u)?inc_:0u; c1 -= (rr_==1u)?inc_:0u; c2 -= (rr_==2u)?inc_:0u; \
    c3 -= (rr_==3u)?inc_:0u; c4 -= (rr_==4u)?inc_:0u; }
  #pragma unroll 1
  for (int r = 0; r < 11; ++r){
    const uint8_t* row = base + r * 528;
    #pragma unroll
    for (int j = 0; j < 11; ++j){ uint32_t q = row[j]; HINC(q); }
  }
  uint64_t packed = 0;
  #pragma unroll 1
  for (int s = 0; s < 8; ++s){
#define KEY(reg, sh, l) (((((reg) >> (sh)) & 0xffu) << 5) | (16u - (uint32_t)(l)))
    uint32_t m0 = umax2(umax2(KEY(c0,0,0),  KEY(c0,8,1)),  umax2(KEY(c0,16,2),  KEY(c0,24,3)));
    uint32_t m1 = umax2(umax2(KEY(c1,0,4),  KEY(c1,8,5)),  umax2(KEY(c1,16,6),  KEY(c1,24,7)));
    uint32_t m2 = umax2(umax2(KEY(c2,0,8),  KEY(c2,8,9)),  umax2(KEY(c2,16,10), KEY(c2,24,11)));
    uint32_t m3 = umax2(umax2(KEY(c3,0,12), KEY(c3,8,13)), umax2(KEY(c3,16,14), KEY(c3,24,15)));
    uint32_t m  = umax2(umax2(umax2(m0, m1), umax2(m2, m3)), KEY(c4,0,16));
#undef KEY
    uint32_t lvl = 16u - (m & 31u);
    packed |= ((uint64_t)lvl) << (8 * s);
    if (s < 7){
      #pragma unroll
      for (int r = 0; r < 11; ++r){
        uint32_t qo = base[r * 528 + s];      HDEC(qo);
        uint32_t qn = base[r * 528 + s + 11]; HINC(qn);
      }
    }
  }
#undef HINC
#undef HDEC
  *(uint64_t*)(xm + img * HW + (h0 + r4) * 512 + w0) = packed;
}

// ---------------------------------------------------------------------------
// block reduction of per-thread su[16]/sq[16] -> partials[block][32]
// ---------------------------------------------------------------------------
__device__ __forceinline__ void reduce16(float* su, float* sq, float* __restrict__ partials){
  __shared__ float lsum[32];
  int tid = threadIdx.x;
  if (tid < 32) lsum[tid] = 0.0f;
  __syncthreads();
  #pragma unroll
  for (int o = 0; o < 16; ++o){
    float s = su[o], q = sq[o];
    #pragma unroll
    for (int off = 32; off >= 1; off >>= 1){
      s += __shfl_xor(s, off);
      q += __shfl_xor(q, off);
    }
    if ((tid & 63) == 0){ atomicAdd(&lsum[o], s); atomicAdd(&lsum[16 + o], q); }
  }
  __syncthreads();
  if (tid < 32) partials[blockIdx.x * 32 + tid] = lsum[tid];
}

// ---------------------------------------------------------------------------
// per-block BN-param computation from a [512][32] partials buffer.
// ---------------------------------------------------------------------------
__device__ __forceinline__ void prep_params(const float* __restrict__ Pp,
                                            const float* __restrict__ g,
                                            const float* __restrict__ bb,
                                            float* prm, float* partS, double* totS){
  int tid = threadIdx.x;
  int o = tid & 31, gg = tid >> 5;            // 8 groups x 32 outputs
  float s0 = 0.0f, s1 = 0.0f, s2 = 0.0f, s3 = 0.0f;
  #pragma unroll
  for (int j = 0; j < 64; j += 4){
    s0 += Pp[(gg * 64 + j    ) * 32 + o];
    s1 += Pp[(gg * 64 + j + 1) * 32 + o];
    s2 += Pp[(gg * 64 + j + 2) * 32 + o];
    s3 += Pp[(gg * 64 + j + 3) * 32 + o];
  }
  partS[gg * 32 + o] = (s0 + s1) + (s2 + s3);
  __syncthreads();
  if (tid < 32){
    double t = 0.0;
    #pragma unroll
    for (int k = 0; k < 8; ++k) t += (double)partS[k * 32 + tid];
    totS[tid] = t;
  }
  __syncthreads();
  if (tid < 16){
    double m = totS[tid] / 524288.0;
    double v = totS[16 + tid] / 524288.0 - m * m;
    float sc = g[tid] / sqrtf((float)v + EPSF);
    prm[tid] = sc;
    prm[16 + tid] = bb[tid] - (float)m * sc;
  }
  __syncthreads();
}

// ---------------------------------------------------------------------------
// K1: stats of p1 = conv1x1(xm). 4 px/thread. grid 512 x 256. -> Pp1
// ---------------------------------------------------------------------------
__global__ __launch_bounds__(256) void k_stats1(const uint8_t* __restrict__ xm,
                                                const float* __restrict__ w1,
                                                const float* __restrict__ b1,
                                                float* __restrict__ partials){
  int t0 = (blockIdx.x * 256 + threadIdx.x) << 2;
  int b = t0 >> 18, hw = t0 & (HW - 1);
  uint32_t q0 = *(const uint32_t*)(xm + (b * 3 + 0) * HW + hw);
  uint32_t q1 = *(const uint32_t*)(xm + (b * 3 + 1) * HW + hw);
  uint32_t q2 = *(const uint32_t*)(xm + (b * 3 + 2) * HW + hw);
  float su[16], sq[16];
  #pragma unroll
  for (int o = 0; o < 16; ++o){ su[o] = 0.0f; sq[o] = 0.0f; }
  #pragma unroll
  for (int px = 0; px < 4; ++px){
    float x0 = (float)((q0 >> (8 * px)) & 0xffu) * 0.0625f;
    float x1 = (float)((q1 >> (8 * px)) & 0xffu) * 0.0625f;
    float x2 = (float)((q2 >> (8 * px)) & 0xffu) * 0.0625f;
    #pragma unroll
    for (int o = 0; o < 16; ++o){
      float v = b1[o] + w1[o*3]*x0 + w1[o*3+1]*x1 + w1[o*3+2]*x2;
      su[o] += v; sq[o] += v * v;
    }
  }
  reduce16(su, sq, partials);
}

// ---------------------------------------------------------------------------
// K2: prologue bn1 params from Pp1; recompute p1, bn1+lrelu, p2 = conv1x1,
// stats -> Pp2.
// ---------------------------------------------------------------------------
__global__ __launch_bounds__(256) void k_stats2(const uint8_t* __restrict__ xm,
                                                const float* __restrict__ w1,
                                                const float* __restrict__ b1,
                                                const float* __restrict__ w2,
                                                const float* __restrict__ b2,
                                                const float* __restrict__ Pp1,
                                                const float* __restrict__ g1,
                                                const float* __restrict__ be1,
                                                float* __restrict__ Pp2){
  __shared__ float prm[32];
  __shared__ float partS[8 * 32];
  __shared__ double totS[32];
  prep_params(Pp1, g1, be1, prm, partS, totS);
  int t0 = (blockIdx.x * 256 + threadIdx.x) << 2;
  int b = t0 >> 18, hw = t0 & (HW - 1);
  uint32_t q0 = *(const uint32_t*)(xm + (b * 3 + 0) * HW + hw);
  uint32_t q1 = *(const uint32_t*)(xm + (b * 3 + 1) * HW + hw);
  uint32_t q2 = *(const uint32_t*)(xm + (b * 3 + 2) * HW + hw);
  float tv[4][16];
  #pragma unroll
  for (int px = 0; px < 4; ++px){
    float x0 = (float)((q0 >> (8 * px)) & 0xffu) * 0.0625f;
    float x1 = (float)((q1 >> (8 * px)) & 0xffu) * 0.0625f;
    float x2 = (float)((q2 >> (8 * px)) & 0xffu) * 0.0625f;
    #pragma unroll
    for (int o = 0; o < 16; ++o){
      float v = b1[o] + w1[o*3]*x0 + w1[o*3+1]*x1 + w1[o*3+2]*x2;
      tv[px][o] = lrelu(v * prm[o] + prm[16 + o]);
    }
  }
  float su[16], sq[16];
  #pragma unroll
  for (int o = 0; o < 16; ++o){ su[o] = 0.0f; sq[o] = 0.0f; }
  #pragma unroll
  for (int o = 0; o < 16; ++o){
    #pragma unroll
    for (int px = 0; px < 4; ++px){
      float acc = b2[o];
      #pragma unroll
      for (int c = 0; c < 16; ++c) acc = fmaf(w2[o*16 + c], tv[px][c], acc);
      su[o] += acc; sq[o] += acc * acc;
    }
  }
  reduce16(su, sq, Pp2);
}

// ---------------------------------------------------------------------------
// K3: prologue bn1 (Pp1) + bn2 (Pp2) params; recompute p2, bn2+lrelu,
// write p (bf16). 4 px/thread.
// ---------------------------------------------------------------------------
__global__ __launch_bounds__(256) void k_prep(const uint8_t* __restrict__ xm,
                                              const float* __restrict__ w1,
                                              const float* __restrict__ b1,
                                              const float* __restrict__ w2,
                                              const float* __restrict__ b2,
                                              const float* __restrict__ Pp1,
                                              const float* __restrict__ g1,
                                              const float* __restrict__ be1,
                                              const float* __restrict__ Pp2,
                                              const float* __restrict__ g2,
                                              const float* __restrict__ be2,
                                              bf16* __restrict__ p){
  __shared__ float prm1[32], prm2[32];
  __shared__ float partS[8 * 32];
  __shared__ double totS[32];
  prep_params(Pp1, g1, be1, prm1, partS, totS);
  prep_params(Pp2, g2, be2, prm2, partS, totS);
  int t0 = (blockIdx.x * 256 + threadIdx.x) << 2;
  int b = t0 >> 18, hw = t0 & (HW - 1);
  uint32_t q0 = *(const uint32_t*)(xm + (b * 3 + 0) * HW + hw);
  uint32_t q1 = *(const uint32_t*)(xm + (b * 3 + 1) * HW + hw);
  uint32_t q2 = *(const uint32_t*)(xm + (b * 3 + 2) * HW + hw);
  float tv[4][16];
  #pragma unroll
  for (int px = 0; px < 4; ++px){
    float x0 = (float)((q0 >> (8 * px)) & 0xffu) * 0.0625f;
    float x1 = (float)((q1 >> (8 * px)) & 0xffu) * 0.0625f;
    float x2 = (float)((q2 >> (8 * px)) & 0xffu) * 0.0625f;
    #pragma unroll
    for (int o = 0; o < 16; ++o){
      float v = b1[o] + w1[o*3]*x0 + w1[o*3+1]*x1 + w1[o*3+2]*x2;
      tv[px][o] = lrelu(v * prm1[o] + prm1[16 + o]);
    }
  }
  #pragma unroll
  for (int o = 0; o < 16; ++o){
    uint32_t w01 = 0, w23 = 0;
    #pragma unroll
    for (int px = 0; px < 4; ++px){
      float acc = b2[o];
      #pragma unroll
      for (int c = 0; c < 16; ++c) acc = fmaf(w2[o*16 + c], tv[px][c], acc);
      float v = lrelu(acc * prm2[o] + prm2[16 + o]);
      uint32_t bits = (uint32_t)f2bu(v);
      if (px == 0) w01 = bits;
      else if (px == 1) w01 |= bits << 16;
      else if (px == 2) w23 = bits;
      else w23 |= bits << 16;
    }
    uint2 ov; ov.x = w01; ov.y = w23;
    *(uint2*)((ushort*)p + (b * 16 + o) * HW + hw) = ov;
  }
}

// ---------------------------------------------------------------------------
// row loader for depthwise conv: 10 values (cols w0-1 .. w0+8), zero-padded.
// ---------------------------------------------------------------------------
__device__ __forceinline__ void load_row10(const ushort* __restrict__ rp, int w0, float* v){
  uint4 cc = *(const uint4*)(rp + w0);
  uint32_t l = (w0 == 0)   ? 0u : (uint32_t)rp[w0 - 1];
  uint32_t r = (w0 == 504) ? 0u : (uint32_t)rp[w0 + 8];
  v[0] = us2f(l);
  v[1] = us2f(cc.x & 0xffffu); v[2] = us2f(cc.x >> 16);
  v[3] = us2f(cc.y & 0xffffu); v[4] = us2f(cc.y >> 16);
  v[5] = us2f(cc.z & 0xffffu); v[6] = us2f(cc.z >> 16);
  v[7] = us2f(cc.w & 0xffffu); v[8] = us2f(cc.w >> 16);
  v[9] = us2f(r);
}

__device__ __forceinline__ void zero_row10(float* v){
  #pragma unroll
  for (int j = 0; j < 10; ++j) v[j] = 0.0f;
}

__device__ __forceinline__ void reduce2(float s, float q, float* __restrict__ partials){
  __shared__ float l2[2];
  int tid = threadIdx.x;
  if (tid < 2) l2[tid] = 0.0f;
  __syncthreads();
  #pragma unroll
  for (int off = 32; off >= 1; off >>= 1){
    s += __shfl_xor(s, off);
    q += __shfl_xor(q, off);
  }
  if ((tid & 63) == 0){ atomicAdd(&l2[0], s); atomicAdd(&l2[1], q); }
  __syncthreads();
  if (tid < 2) partials[blockIdx.x * 2 + tid] = l2[tid];
}

// ---------------------------------------------------------------------------
// A: conv stats of p + write c0 = conv(p) (bf16). grid 4096.
// ---------------------------------------------------------------------------
__global__ __launch_bounds__(256) void k_convstat(const bf16* __restrict__ d,
                                                  const float* __restrict__ dw,
                                                  float* __restrict__ P1,
                                                  bf16* __restrict__ cout){
  int bid = blockIdx.x;
  int plane = bid >> 7, rg = bid & 127;
  int f = plane & 15;
  int tid = threadIdx.x;
  int h  = (rg << 2) + (tid >> 6);
  int w0 = (tid & 63) << 3;
  const ushort* pl = (const ushort*)d + plane * HW;
  float wf[9];
  #pragma unroll
  for (int i = 0; i < 9; ++i) wf[i] = dw[f * 9 + i];
  float v[3][10];
  #pragma unroll
  for (int dy = 0; dy < 3; ++dy){
    int row = h + dy - 1;
    if ((unsigned)row < 512u) load_row10(pl + row * 512, w0, v[dy]);
    else zero_row10(v[dy]);
  }
  float s = 0.0f, q = 0.0f;
  uint32_t cb[4];
  #pragma unroll
  for (int k = 0; k < 8; ++k){
    float acc = 0.0f;
    #pragma unroll
    for (int dy = 0; dy < 3; ++dy)
      #pragma unroll
      for (int dx = 0; dx < 3; ++dx)
        acc = fmaf(wf[dy*3 + dx], v[dy][k + dx], acc);
    s += acc; q += acc * acc;
    uint32_t bits = (uint32_t)f2bu(acc);
    if ((k & 1) == 0) cb[k >> 1] = bits; else cb[k >> 1] |= bits << 16;
  }
  uint4 cv; cv.x = cb[0]; cv.y = cb[1]; cv.z = cb[2]; cv.w = cb[3];
  *(uint4*)((ushort*)cout + plane * HW + h * 512 + w0) = cv;
  reduce2(s, q, P1);
}

// ---------------------------------------------------------------------------
// wave-parallel channel-f sum of a [32 planes][128 rg][2] partials buffer.
// ---------------------------------------------------------------------------
__device__ __forceinline__ void chan_sum_wave(const float* __restrict__ P, int f, int lane,
                                              double& S, double& Q){
  S = 0.0; Q = 0.0;
  #pragma unroll
  for (int i = 0; i < 4; ++i){
    int e = lane + i * 64;                    // 0..255
    int blk = (((e >> 7) * 16 + f) << 7) + (e & 127);
    S += (double)P[blk * 2];
    Q += (double)P[blk * 2 + 1];
  }
  #pragma unroll
  for (int off = 32; off >= 1; off >>= 1){
    S += __shfl_xor(S, off);
    Q += __shfl_xor(Q, off);
  }
}

// ---------------------------------------------------------------------------
// FUSED loop kernel (c-carry, NO d-store). grid 4096, 256 threads.
// ---------------------------------------------------------------------------
__global__ __launch_bounds__(256) void k_bnfused(const bf16* __restrict__ cin,
                                                 const float* __restrict__ dw,
                                                 const float* __restrict__ gd,
                                                 const float* __restrict__ bd,
                                                 const float* __restrict__ P1in,
                                                 bf16* __restrict__ cout,
                                                 float* __restrict__ P2out,
                                                 float* __restrict__ P1out,
                                                 float* __restrict__ dparams,
                                                 int t, int write_c){
  __shared__ ushort strip[6][512];
  __shared__ float acc4[4];
  int bid = blockIdx.x;
  int plane = bid >> 7, rg = bid & 127;
  int f = plane & 15;
  int tid = threadIdx.x;

  double S, Q;
  chan_sum_wave(P1in, f, tid & 63, S, Q);
  float sc, sh;
  {
    double m = S / 524288.0;
    double v = Q / 524288.0 - m * m;
    sc = gd[f] / sqrtf((float)v + EPSF);
    sh = bd[f] - (float)m * sc;
  }
  if (plane < 16 && rg == 0 && tid == 0){
    dparams[512 + t * 32 + 2 * f]     = sc;
    dparams[512 + t * 32 + 2 * f + 1] = sh;
  }
  if (tid < 4) acc4[tid] = 0.0f;

  int h0 = rg << 2;
  int h  = h0 + (tid >> 6);
  int w0 = (tid & 63) << 3;
  const ushort* cpl = (const ushort*)cin + plane * HW;

  float s2 = 0.0f, q2 = 0.0f;
  {
    uint4 cv = *(const uint4*)(cpl + h * 512 + w0);
    float cf[8];
    cf[0] = us2f(cv.x & 0xffffu); cf[1] = us2f(cv.x >> 16);
    cf[2] = us2f(cv.y & 0xffffu); cf[3] = us2f(cv.y >> 16);
    cf[4] = us2f(cv.z & 0xffffu); cf[5] = us2f(cv.z >> 16);
    cf[6] = us2f(cv.w & 0xffffu); cf[7] = us2f(cv.w >> 16);
    uint32_t ob[4];
    #pragma unroll
    for (int k = 0; k < 8; ++k){
      float vv = lrelu(fmaf(cf[k], sc, sh));
      uint32_t bits = (uint32_t)f2bu(vv);
      if ((k & 1) == 0) ob[k >> 1] = bits; else ob[k >> 1] |= bits << 16;
      s2 += vv; q2 += vv * vv;
    }
    uint4 ov; ov.x = ob[0]; ov.y = ob[1]; ov.z = ob[2]; ov.w = ob[3];
    *(uint4*)&strip[1 + (tid >> 6)][w0] = ov;
  }

  if (tid < 128){
    int hh = (tid < 64) ? (h0 - 1) : (h0 + 4);
    int si = (tid < 64) ? 0 : 5;
    int wh0 = (tid & 63) << 3;
    uint4 hv; hv.x = 0; hv.y = 0; hv.z = 0; hv.w = 0;
    if ((unsigned)hh < 512u){
      uint4 cv = *(const uint4*)(cpl + hh * 512 + wh0);
      float cf[8];
      cf[0] = us2f(cv.x & 0xffffu); cf[1] = us2f(cv.x >> 16);
      cf[2] = us2f(cv.y & 0xffffu); cf[3] = us2f(cv.y >> 16);
      cf[4] = us2f(cv.z & 0xffffu); cf[5] = us2f(cv.z >> 16);
      cf[6] = us2f(cv.w & 0xffffu); cf[7] = us2f(cv.w >> 16);
      uint32_t hb[4];
      #pragma unroll
      for (int k = 0; k < 8; ++k){
        float vv = lrelu(fmaf(cf[k], sc, sh));
        uint32_t bits = (uint32_t)f2bu(vv);
        if ((k & 1) == 0) hb[k >> 1] = bits; else hb[k >> 1] |= bits << 16;
      }
      hv.x = hb[0]; hv.y = hb[1]; hv.z = hb[2]; hv.w = hb[3];
    }
    *(uint4*)&strip[si][wh0] = hv;
  }
  __syncthreads();

  float wf[9];
  #pragma unroll
  for (int i = 0; i < 9; ++i) wf[i] = dw[f * 9 + i];
  float s1 = 0.0f, q1 = 0.0f;
  {
    int si = 1 + (tid >> 6);
    float v[3][10];
    #pragma unroll
    for (int dy = 0; dy < 3; ++dy)
      load_row10(&strip[si - 1 + dy][0], w0, v[dy]);
    uint32_t cb[4];
    #pragma unroll
    for (int k = 0; k < 8; ++k){
      float acc = 0.0f;
      #pragma unroll
      for (int dy = 0; dy < 3; ++dy)
        #pragma unroll
        for (int dx = 0; dx < 3; ++dx)
          acc = fmaf(wf[dy*3 + dx], v[dy][k + dx], acc);
      s1 += acc; q1 += acc * acc;
      uint32_t bits = (uint32_t)f2bu(acc);
      if ((k & 1) == 0) cb[k >> 1] = bits; else cb[k >> 1] |= bits << 16;
    }
    if (write_c){
      uint4 cv2; cv2.x = cb[0]; cv2.y = cb[1]; cv2.z = cb[2]; cv2.w = cb[3];
      *(uint4*)((ushort*)cout + plane * HW + h * 512 + w0) = cv2;
    }
  }

  #pragma unroll
  for (int off = 32; off >= 1; off >>= 1){
    s2 += __shfl_xor(s2, off);
    q2 += __shfl_xor(q2, off);
    s1 += __shfl_xor(s1, off);
    q1 += __shfl_xor(q1, off);
  }
  if ((tid & 63) == 0){
    atomicAdd(&acc4[0], s2); atomicAdd(&acc4[1], q2);
    atomicAdd(&acc4[2], s1); atomicAdd(&acc4[3], q1);
  }
  __syncthreads();
  if (tid < 2)      P2out[bid * 2 + tid]       = acc4[tid];
  else if (tid < 4) P1out[bid * 2 + (tid - 2)] = acc4[tid];
}

// ---------------------------------------------------------------------------
// k_fin_all: 80 wdt/hgt param quadruples, one (t,f) pair per wave. grid 20.
// ---------------------------------------------------------------------------
__global__ __launch_bounds__(256) void k_fin_all(const float* __restrict__ P2,
                                                 const float* __restrict__ ww,
                                                 const float* __restrict__ gw,
                                                 const float* __restrict__ bw,
                                                 const float* __restrict__ wh,
                                                 const float* __restrict__ gh,
                                                 const float* __restrict__ bh,
                                                 float* __restrict__ dparams){
  int tid = threadIdx.x;
  int wid = tid >> 6, lane = tid & 63;
  int pair = blockIdx.x * 4 + wid;              // 0..79
  int t = pair >> 4, f = pair & 15;
  double S, Q;
  chan_sum_wave(P2 + t * 8192, f, lane, S, Q);
  if (lane == 0){
    float m = (float)(S / 524288.0);
    float v = (float)(Q / 524288.0) - m * m;
    float sw = ww[f] * gw[f] / sqrtf(ww[f] * ww[f] * v + EPSF);
    float tw = bw[f] - m * sw;
    float s2 = wh[f] * gh[f] / sqrtf(wh[f] * wh[f] * v + EPSF);
    float t2 = bh[f] - m * s2;
    dparams[t * 64 + f]      = sw;
    dparams[t * 64 + 16 + f] = tw;
    dparams[t * 64 + 32 + f] = s2;
    dparams[t * 64 + 48 + f] = t2;
  }
}

// ---------------------------------------------------------------------------
// F: assemble out. 16 px/thread (grid 1024); ALL 24 uint4 loads issued
// up-front (384 B/thread in flight -> 2x MLP vs r14's 12-load version),
// then two 8-px compute+store stages. d_t recomputed from c_t + (sc,sh).
// ---------------------------------------------------------------------------
__device__ __forceinline__ void conv8(uint4 cc, float* v){
  v[0] = us2f(cc.x & 0xffffu); v[1] = us2f(cc.x >> 16);
  v[2] = us2f(cc.y & 0xffffu); v[3] = us2f(cc.y >> 16);
  v[4] = us2f(cc.z & 0xffffu); v[5] = us2f(cc.z >> 16);
  v[6] = us2f(cc.w & 0xffffu); v[7] = us2f(cc.w >> 16);
}

__global__ __launch_bounds__(256) void k_final(const bf16* __restrict__ p,
                                               const bf16* __restrict__ c1,
                                               const bf16* __restrict__ c2,
                                               const bf16* __restrict__ c3,
                                               const bf16* __restrict__ c4,
                                               const bf16* __restrict__ c5,
                                               const float* __restrict__ dparams,
                                               float* __restrict__ out){
  int tid = threadIdx.x;
  int f = blockIdx.x >> 6;                      // 64 blocks per f
  int idx = ((blockIdx.x & 63) << 8) + tid;     // 0..16383
  int hw = idx << 4;                            // 16 px/thread
  int fo = f * HW + hw;
  int f1 = (16 + f) * HW + hw;

  // ---- issue ALL 24 loads up front ----
  uint4 Ap0 = *(const uint4*)((const ushort*)p  + fo);
  uint4 Ap1 = *(const uint4*)((const ushort*)p  + f1);
  uint4 A0a = *(const uint4*)((const ushort*)c1 + fo);
  uint4 A0b = *(const uint4*)((const ushort*)c1 + f1);
  uint4 A1a = *(const uint4*)((const ushort*)c2 + fo);
  uint4 A1b = *(const uint4*)((const ushort*)c2 + f1);
  uint4 A2a = *(const uint4*)((const ushort*)c3 + fo);
  uint4 A2b = *(const uint4*)((const ushort*)c3 + f1);
  uint4 A3a = *(const uint4*)((const ushort*)c4 + fo);
  uint4 A3b = *(const uint4*)((const ushort*)c4 + f1);
  uint4 A4a = *(const uint4*)((const ushort*)c5 + fo);
  uint4 A4b = *(const uint4*)((const ushort*)c5 + f1);
  uint4 Bp0 = *(const uint4*)((const ushort*)p  + fo + 8);
  uint4 Bp1 = *(const uint4*)((const ushort*)p  + f1 + 8);
  uint4 B0a = *(const uint4*)((const ushort*)c1 + fo + 8);
  uint4 B0b = *(const uint4*)((const ushort*)c1 + f1 + 8);
  uint4 B1a = *(const uint4*)((const ushort*)c2 + fo + 8);
  uint4 B1b = *(const uint4*)((const ushort*)c2 + f1 + 8);
  uint4 B2a = *(const uint4*)((const ushort*)c3 + fo + 8);
  uint4 B2b = *(const uint4*)((const ushort*)c3 + f1 + 8);
  uint4 B3a = *(const uint4*)((const ushort*)c4 + fo + 8);
  uint4 B3b = *(const uint4*)((const ushort*)c4 + f1 + 8);
  uint4 B4a = *(const uint4*)((const ushort*)c5 + fo + 8);
  uint4 B4b = *(const uint4*)((const ushort*)c5 + f1 + 8);

  float swA[5], twA[5], shA[5], thA[5], scA[5], sbA[5];
  #pragma unroll
  for (int t = 0; t < 5; ++t){
    swA[t] = dparams[t * 64 + f];
    twA[t] = dparams[t * 64 + 16 + f];
    shA[t] = dparams[t * 64 + 32 + f];
    thA[t] = dparams[t * 64 + 48 + f];
    scA[t] = dparams[512 + t * 32 + 2 * f];
    sbA[t] = dparams[512 + t * 32 + 2 * f + 1];
  }

  // ---- stage A: px 0..7 ----
  {
    float pf[8], pg[8];
    conv8(Ap0, pf); conv8(Ap1, pg);
    float a00[8], a01[8], a10[8], a11[8];
    #pragma unroll
    for (int k = 0; k < 8; ++k){ a00[k]=pf[k]; a01[k]=pg[k]; a10[k]=pf[k]; a11[k]=pg[k]; }
    uint4 ra[5] = { A0a, A1a, A2a, A3a, A4a };
    uint4 rb[5] = { A0b, A1b, A2b, A3b, A4b };
    #pragma unroll
    for (int t = 0; t < 5; ++t){
      float cv0[8], cv1[8];
      conv8(ra[t], cv0); conv8(rb[t], cv1);
      float sw = swA[t], tw = twA[t], sh = shA[t], th = thA[t];
      float sc = scA[t], sb = sbA[t];
      #pragma unroll
      for (int k = 0; k < 8; ++k){
        float dv0 = lrelu(fmaf(cv0[k], sc, sb));
        float dv1 = lrelu(fmaf(cv1[k], sc, sb));
        a00[k] += lrelu(fmaf(dv0, sw, tw));
        a01[k] += lrelu(fmaf(dv0, sh, th));
        a10[k] += lrelu(fmaf(dv1, sw, tw));
        a11[k] += lrelu(fmaf(dv1, sh, th));
      }
    }
    #pragma unroll
    for (int half = 0; half < 2; ++half){
      float4 v0 = { a00[half*4+0], a00[half*4+1], a00[half*4+2], a00[half*4+3] };
      float4 v1 = { a01[half*4+0], a01[half*4+1], a01[half*4+2], a01[half*4+3] };
      float4 v2 = { a10[half*4+0], a10[half*4+1], a10[half*4+2], a10[half*4+3] };
      float4 v3 = { a11[half*4+0], a11[half*4+1], a11[half*4+2], a11[half*4+3] };
      *(float4*)(out + f * HW + hw + half*4)        = v0;
      *(float4*)(out + (16 + f) * HW + hw + half*4) = v1;
      *(float4*)(out + (32 + f) * HW + hw + half*4) = v2;
      *(float4*)(out + (48 + f) * HW + hw + half*4) = v3;
    }
  }

  // ---- stage B: px 8..15 ----
  {
    int hwb = hw + 8;
    float pf[8], pg[8];
    conv8(Bp0, pf); conv8(Bp1, pg);
    float a00[8], a01[8], a10[8], a11[8];
    #pragma unroll
    for (int k = 0; k < 8; ++k){ a00[k]=pf[k]; a01[k]=pg[k]; a10[k]=pf[k]; a11[k]=pg[k]; }
    uint4 ra[5] = { B0a, B1a, B2a, B3a, B4a };
    uint4 rb[5] = { B0b, B1b, B2b, B3b, B4b };
    #pragma unroll
    for (int t = 0; t < 5; ++t){
      float cv0[8], cv1[8];
      conv8(ra[t], cv0); conv8(rb[t], cv1);
      float sw = swA[t], tw = twA[t], sh = shA[t], th = thA[t];
      float sc = scA[t], sb = sbA[t];
      #pragma unroll
      for (int k = 0; k < 8; ++k){
        float dv0 = lrelu(fmaf(cv0[k], sc, sb));
        float dv1 = lrelu(fmaf(cv1[k], sc, sb));
        a00[k] += lrelu(fmaf(dv0, sw, tw));
        a01[k] += lrelu(fmaf(dv0, sh, th));
        a10[k] += lrelu(fmaf(dv1, sw, tw));
        a11[k] += lrelu(fmaf(dv1, sh, th));
      }
    }
    #pragma unroll
    for (int half = 0; half < 2; ++half){
      float4 v0 = { a00[half*4+0], a00[half*4+1], a00[half*4+2], a00[half*4+3] };
      float4 v1 = { a01[half*4+0], a01[half*4+1], a01[half*4+2], a01[half*4+3] };
      float4 v2 = { a10[half*4+0], a10[half*4+1], a10[half*4+2], a10[half*4+3] };
      float4 v3 = { a11[half*4+0], a11[half*4+1], a11[half*4+2], a11[half*4+3] };
      *(float4*)(out + f * HW + hwb + half*4)        = v0;
      *(float4*)(out + (16 + f) * HW + hwb + half*4) = v1;
      *(float4*)(out + (32 + f) * HW + hwb + half*4) = v2;
      *(float4*)(out + (48 + f) * HW + hwb + half*4) = v3;
    }
  }
}

// ---------------------------------------------------------------------------
extern "C" void kernel_launch(void* const* d_in, const int* in_sizes, int n_in,
                              void* d_out, int out_size, void* d_ws, size_t ws_size,
                              hipStream_t stream){
  (void)in_sizes; (void)n_in; (void)out_size;
  const float* x   = (const float*)d_in[0];
  const float* w1  = (const float*)d_in[1];
  const float* b1  = (const float*)d_in[2];
  const float* g1  = (const float*)d_in[3];
  const float* be1 = (const float*)d_in[4];
  const float* w2  = (const float*)d_in[5];
  const float* b2  = (const float*)d_in[6];
  const float* g2  = (const float*)d_in[7];
  const float* be2 = (const float*)d_in[8];
  const float* dw  = (const float*)d_in[9];
  const float* gd  = (const float*)d_in[10];
  const float* bd  = (const float*)d_in[11];
  const float* ww  = (const float*)d_in[12];
  const float* gw  = (const float*)d_in[13];
  const float* bw  = (const float*)d_in[14];
  const float* wh  = (const float*)d_in[15];
  const float* gh  = (const float*)d_in[16];
  const float* bh  = (const float*)d_in[17];
  float* out = (float*)d_out;

  char* ws = (char*)d_ws;
  size_t off = 0;
  auto alloc = [&](size_t sz) -> void* {
    void* ptr = ws + off;
    off = (off + sz + 4095) & ~(size_t)4095;
    return ptr;
  };
  uint8_t* xm    = (uint8_t*)alloc((size_t)6 * HW);
  bf16*    p     = (bf16*)   alloc((size_t)32 * HW * 2);
  bf16*    cbuf[5];
  for (int i = 0; i < 5; ++i) cbuf[i] = (bf16*)alloc((size_t)32 * HW * 2);
  float*   Pp1    = (float*)  alloc((size_t)512 * 32 * 4);
  float*   Pp2    = (float*)  alloc((size_t)512 * 32 * 4);
  float*   P1a    = (float*)  alloc((size_t)4096 * 2 * 4);
  float*   P1b    = (float*)  alloc((size_t)4096 * 2 * 4);
  float*   P2     = (float*)  alloc((size_t)5 * 4096 * 2 * 4);
  float*   dparams= (float*)  alloc(4096);
  if (ws_size < off) return;   // workspace too small: fail visibly (untouched out)

  k_mode     <<<dim3(768), dim3(256), 0, stream>>>(x, xm);
  k_stats1   <<<dim3(512), dim3(256), 0, stream>>>(xm, w1, b1, Pp1);
  k_stats2   <<<dim3(512), dim3(256), 0, stream>>>(xm, w1, b1, w2, b2,
                                                   Pp1, g1, be1, Pp2);
  k_prep     <<<dim3(512), dim3(256), 0, stream>>>(xm, w1, b1, w2, b2,
                                                   Pp1, g1, be1, Pp2, g2, be2, p);
  k_convstat <<<dim3(4096), dim3(256), 0, stream>>>(p, dw, P1a, cbuf[0]);

  float* Pin = P1a; float* Pout = P1b;
  for (int t = 0; t < 5; ++t){
    k_bnfused<<<dim3(4096), dim3(256), 0, stream>>>(
        cbuf[t], dw, gd, bd, Pin,
        (t < 4) ? cbuf[t + 1] : cbuf[0],      // dummy target when !write_c
        P2 + t * 8192, Pout, dparams, t, (t < 4) ? 1 : 0);
    float* tmp = Pin; Pin = Pout; Pout = tmp;
  }
  k_fin_all<<<dim3(20), dim3(256), 0, stream>>>(P2, ww, gw, bw, wh, gh, bh, dparams);
  k_final<<<dim3(1024), dim3(256), 0, stream>>>(p, cbuf[0], cbuf[1], cbuf[2],
                                                cbuf[3], cbuf[4], dparams, out);
}

// Round 16
// 214.863 us; speedup vs baseline: 1.0797x; 1.0797x over previous
//
#include <hip/hip_runtime.h>
#include <hip/hip_bf16.h>
#include <stdint.h>
#include <stddef.h>

#define HW 262144          // 512*512
#define EPSF 1e-5f

typedef __hip_bfloat16 bf16;

__device__ __forceinline__ float us2f(uint32_t u){
  union { uint32_t i; float f; } c; c.i = u << 16; return c.f;
}
__device__ __forceinline__ ushort f2bu(float v){
  union { bf16 h; ushort u; } c; c.h = __float2bfloat16(v); return c.u;
}
__device__ __forceinline__ float lrelu(float v){ return v > 0.0f ? v : 0.01f * v; }
__device__ __forceinline__ uint32_t umax2(uint32_t a, uint32_t b){ return a > b ? a : b; }

// ---------------------------------------------------------------------------
// K0: 11x11 mode filter with FUSED quantize+reflect-pad staging (vectorized).
// ---------------------------------------------------------------------------
__global__ __launch_bounds__(256) void k_mode(const float* __restrict__ x,
                                              uint8_t* __restrict__ xm){
  __shared__ uint8_t tile[14 * 528];
  int tid = threadIdx.x;
  int img = blockIdx.x >> 7;
  int h0  = (blockIdx.x & 127) << 2;          // first output row of block
  {
    const float* xp = x + img * HW;
    // interior: 14 rows x 128 dwords (ws = 4*g), one u32 store each
    #pragma unroll 1
    for (int idx = tid; idx < 14 * 128; idx += 256){
      int r = idx >> 7, g = idx & 127;
      int hs = h0 + r - 5; hs = hs < 0 ? -hs : hs; if (hs > 511) hs = 1022 - hs;
      int ws = g << 2;
      float4 v = *(const float4*)(xp + hs * 512 + ws);
      uint32_t b0 = (uint32_t)(uint8_t)(int)rintf((v.x * 255.0f) / 16.0f);
      uint32_t b1 = (uint32_t)(uint8_t)(int)rintf((v.y * 255.0f) / 16.0f);
      uint32_t b2 = (uint32_t)(uint8_t)(int)rintf((v.z * 255.0f) / 16.0f);
      uint32_t b3 = (uint32_t)(uint8_t)(int)rintf((v.w * 255.0f) / 16.0f);
      *(uint32_t*)&tile[r * 528 + 8 + ws] = b0 | (b1 << 8) | (b2 << 16) | (b3 << 24);
    }
    // halo: 14 rows x 10 cols (pw 0..4 and 517..521), scalar bytes
    if (tid < 140){
      int r = tid / 10, i = tid % 10;
      int pw = (i < 5) ? i : (512 + i);      // 0..4 or 517..521
      int hs = h0 + r - 5; hs = hs < 0 ? -hs : hs; if (hs > 511) hs = 1022 - hs;
      int ws = pw - 5; ws = ws < 0 ? -ws : ws; if (ws > 511) ws = 1022 - ws;
      float v = xp[hs * 512 + ws];
      tile[r * 528 + 3 + pw] = (uint8_t)(int)rintf((v * 255.0f) / 16.0f);
    }
  }
  __syncthreads();
  int r4 = tid >> 6;                          // row within block 0..3
  int w0 = (tid & 63) << 3;                   // 0..504
  const uint8_t* base = tile + r4 * 528 + 3 + w0;
  uint32_t c0 = 0, c1 = 0, c2 = 0, c3 = 0, c4 = 0;
#define HINC(q) { uint32_t inc_ = 1u << (((q) & 3u) << 3); uint32_t rr_ = (q) >> 2; \
    c0 += (rr_==0u)?inc_:0u; c1 += (rr_==1u)?inc_:0u; c2 += (rr_==2u)?inc_:0u; \
    c3 += (rr_==3u)?inc_:0u; c4 += (rr_==4u)?inc_:0u; }
#define HDEC(q) { uint32_t inc_ = 1u << (((q) & 3u) << 3); uint32_t rr_ = (q) >> 2; \
    c0 -= (rr_==0u)?inc_:0u; c1 -= (rr_==1u)?inc_:0u; c2 -= (rr_==2u)?inc_:0u; \
    c3 -= (rr_==3u)?inc_:0u; c4 -= (rr_==4u)?inc_:0u; }
  #pragma unroll 1
  for (int r = 0; r < 11; ++r){
    const uint8_t* row = base + r * 528;
    #pragma unroll
    for (int j = 0; j < 11; ++j){ uint32_t q = row[j]; HINC(q); }
  }
  uint64_t packed = 0;
  #pragma unroll 1
  for (int s = 0; s < 8; ++s){
#define KEY(reg, sh, l) (((((reg) >> (sh)) & 0xffu) << 5) | (16u - (uint32_t)(l)))
    uint32_t m0 = umax2(umax2(KEY(c0,0,0),  KEY(c0,8,1)),  umax2(KEY(c0,16,2),  KEY(c0,24,3)));
    uint32_t m1 = umax2(umax2(KEY(c1,0,4),  KEY(c1,8,5)),  umax2(KEY(c1,16,6),  KEY(c1,24,7)));
    uint32_t m2 = umax2(umax2(KEY(c2,0,8),  KEY(c2,8,9)),  umax2(KEY(c2,16,10), KEY(c2,24,11)));
    uint32_t m3 = umax2(umax2(KEY(c3,0,12), KEY(c3,8,13)), umax2(KEY(c3,16,14), KEY(c3,24,15)));
    uint32_t m  = umax2(umax2(umax2(m0, m1), umax2(m2, m3)), KEY(c4,0,16));
#undef KEY
    uint32_t lvl = 16u - (m & 31u);
    packed |= ((uint64_t)lvl) << (8 * s);
    if (s < 7){
      #pragma unroll
      for (int r = 0; r < 11; ++r){
        uint32_t qo = base[r * 528 + s];      HDEC(qo);
        uint32_t qn = base[r * 528 + s + 11]; HINC(qn);
      }
    }
  }
#undef HINC
#undef HDEC
  *(uint64_t*)(xm + img * HW + (h0 + r4) * 512 + w0) = packed;
}

// ---------------------------------------------------------------------------
// block reduction of per-thread su[16]/sq[16] -> partials[block][32]
// ---------------------------------------------------------------------------
__device__ __forceinline__ void reduce16(float* su, float* sq, float* __restrict__ partials){
  __shared__ float lsum[32];
  int tid = threadIdx.x;
  if (tid < 32) lsum[tid] = 0.0f;
  __syncthreads();
  #pragma unroll
  for (int o = 0; o < 16; ++o){
    float s = su[o], q = sq[o];
    #pragma unroll
    for (int off = 32; off >= 1; off >>= 1){
      s += __shfl_xor(s, off);
      q += __shfl_xor(q, off);
    }
    if ((tid & 63) == 0){ atomicAdd(&lsum[o], s); atomicAdd(&lsum[16 + o], q); }
  }
  __syncthreads();
  if (tid < 32) partials[blockIdx.x * 32 + tid] = lsum[tid];
}

// ---------------------------------------------------------------------------
// per-block BN-param computation from a [512][32] partials buffer.
// ---------------------------------------------------------------------------
__device__ __forceinline__ void prep_params(const float* __restrict__ Pp,
                                            const float* __restrict__ g,
                                            const float* __restrict__ bb,
                                            float* prm, float* partS, double* totS){
  int tid = threadIdx.x;
  int o = tid & 31, gg = tid >> 5;            // 8 groups x 32 outputs
  float s0 = 0.0f, s1 = 0.0f, s2 = 0.0f, s3 = 0.0f;
  #pragma unroll
  for (int j = 0; j < 64; j += 4){
    s0 += Pp[(gg * 64 + j    ) * 32 + o];
    s1 += Pp[(gg * 64 + j + 1) * 32 + o];
    s2 += Pp[(gg * 64 + j + 2) * 32 + o];
    s3 += Pp[(gg * 64 + j + 3) * 32 + o];
  }
  partS[gg * 32 + o] = (s0 + s1) + (s2 + s3);
  __syncthreads();
  if (tid < 32){
    double t = 0.0;
    #pragma unroll
    for (int k = 0; k < 8; ++k) t += (double)partS[k * 32 + tid];
    totS[tid] = t;
  }
  __syncthreads();
  if (tid < 16){
    double m = totS[tid] / 524288.0;
    double v = totS[16 + tid] / 524288.0 - m * m;
    float sc = g[tid] / sqrtf((float)v + EPSF);
    prm[tid] = sc;
    prm[16 + tid] = bb[tid] - (float)m * sc;
  }
  __syncthreads();
}

// ---------------------------------------------------------------------------
// K1: stats of p1 = conv1x1(xm). 4 px/thread. grid 512 x 256. -> Pp1
// ---------------------------------------------------------------------------
__global__ __launch_bounds__(256) void k_stats1(const uint8_t* __restrict__ xm,
                                                const float* __restrict__ w1,
                                                const float* __restrict__ b1,
                                                float* __restrict__ partials){
  int t0 = (blockIdx.x * 256 + threadIdx.x) << 2;
  int b = t0 >> 18, hw = t0 & (HW - 1);
  uint32_t q0 = *(const uint32_t*)(xm + (b * 3 + 0) * HW + hw);
  uint32_t q1 = *(const uint32_t*)(xm + (b * 3 + 1) * HW + hw);
  uint32_t q2 = *(const uint32_t*)(xm + (b * 3 + 2) * HW + hw);
  float su[16], sq[16];
  #pragma unroll
  for (int o = 0; o < 16; ++o){ su[o] = 0.0f; sq[o] = 0.0f; }
  #pragma unroll
  for (int px = 0; px < 4; ++px){
    float x0 = (float)((q0 >> (8 * px)) & 0xffu) * 0.0625f;
    float x1 = (float)((q1 >> (8 * px)) & 0xffu) * 0.0625f;
    float x2 = (float)((q2 >> (8 * px)) & 0xffu) * 0.0625f;
    #pragma unroll
    for (int o = 0; o < 16; ++o){
      float v = b1[o] + w1[o*3]*x0 + w1[o*3+1]*x1 + w1[o*3+2]*x2;
      su[o] += v; sq[o] += v * v;
    }
  }
  reduce16(su, sq, partials);
}

// ---------------------------------------------------------------------------
// K2: prologue bn1 params from Pp1; recompute p1, bn1+lrelu, p2 = conv1x1,
// stats -> Pp2.
// ---------------------------------------------------------------------------
__global__ __launch_bounds__(256) void k_stats2(const uint8_t* __restrict__ xm,
                                                const float* __restrict__ w1,
                                                const float* __restrict__ b1,
                                                const float* __restrict__ w2,
                                                const float* __restrict__ b2,
                                                const float* __restrict__ Pp1,
                                                const float* __restrict__ g1,
                                                const float* __restrict__ be1,
                                                float* __restrict__ Pp2){
  __shared__ float prm[32];
  __shared__ float partS[8 * 32];
  __shared__ double totS[32];
  prep_params(Pp1, g1, be1, prm, partS, totS);
  int t0 = (blockIdx.x * 256 + threadIdx.x) << 2;
  int b = t0 >> 18, hw = t0 & (HW - 1);
  uint32_t q0 = *(const uint32_t*)(xm + (b * 3 + 0) * HW + hw);
  uint32_t q1 = *(const uint32_t*)(xm + (b * 3 + 1) * HW + hw);
  uint32_t q2 = *(const uint32_t*)(xm + (b * 3 + 2) * HW + hw);
  float tv[4][16];
  #pragma unroll
  for (int px = 0; px < 4; ++px){
    float x0 = (float)((q0 >> (8 * px)) & 0xffu) * 0.0625f;
    float x1 = (float)((q1 >> (8 * px)) & 0xffu) * 0.0625f;
    float x2 = (float)((q2 >> (8 * px)) & 0xffu) * 0.0625f;
    #pragma unroll
    for (int o = 0; o < 16; ++o){
      float v = b1[o] + w1[o*3]*x0 + w1[o*3+1]*x1 + w1[o*3+2]*x2;
      tv[px][o] = lrelu(v * prm[o] + prm[16 + o]);
    }
  }
  float su[16], sq[16];
  #pragma unroll
  for (int o = 0; o < 16; ++o){ su[o] = 0.0f; sq[o] = 0.0f; }
  #pragma unroll
  for (int o = 0; o < 16; ++o){
    #pragma unroll
    for (int px = 0; px < 4; ++px){
      float acc = b2[o];
      #pragma unroll
      for (int c = 0; c < 16; ++c) acc = fmaf(w2[o*16 + c], tv[px][c], acc);
      su[o] += acc; sq[o] += acc * acc;
    }
  }
  reduce16(su, sq, Pp2);
}

// ---------------------------------------------------------------------------
// K3: prologue bn1 (Pp1) + bn2 (Pp2) params; recompute p2, bn2+lrelu,
// write p (bf16). 4 px/thread.
// ---------------------------------------------------------------------------
__global__ __launch_bounds__(256) void k_prep(const uint8_t* __restrict__ xm,
                                              const float* __restrict__ w1,
                                              const float* __restrict__ b1,
                                              const float* __restrict__ w2,
                                              const float* __restrict__ b2,
                                              const float* __restrict__ Pp1,
                                              const float* __restrict__ g1,
                                              const float* __restrict__ be1,
                                              const float* __restrict__ Pp2,
                                              const float* __restrict__ g2,
                                              const float* __restrict__ be2,
                                              bf16* __restrict__ p){
  __shared__ float prm1[32], prm2[32];
  __shared__ float partS[8 * 32];
  __shared__ double totS[32];
  prep_params(Pp1, g1, be1, prm1, partS, totS);
  prep_params(Pp2, g2, be2, prm2, partS, totS);
  int t0 = (blockIdx.x * 256 + threadIdx.x) << 2;
  int b = t0 >> 18, hw = t0 & (HW - 1);
  uint32_t q0 = *(const uint32_t*)(xm + (b * 3 + 0) * HW + hw);
  uint32_t q1 = *(const uint32_t*)(xm + (b * 3 + 1) * HW + hw);
  uint32_t q2 = *(const uint32_t*)(xm + (b * 3 + 2) * HW + hw);
  float tv[4][16];
  #pragma unroll
  for (int px = 0; px < 4; ++px){
    float x0 = (float)((q0 >> (8 * px)) & 0xffu) * 0.0625f;
    float x1 = (float)((q1 >> (8 * px)) & 0xffu) * 0.0625f;
    float x2 = (float)((q2 >> (8 * px)) & 0xffu) * 0.0625f;
    #pragma unroll
    for (int o = 0; o < 16; ++o){
      float v = b1[o] + w1[o*3]*x0 + w1[o*3+1]*x1 + w1[o*3+2]*x2;
      tv[px][o] = lrelu(v * prm1[o] + prm1[16 + o]);
    }
  }
  #pragma unroll
  for (int o = 0; o < 16; ++o){
    uint32_t w01 = 0, w23 = 0;
    #pragma unroll
    for (int px = 0; px < 4; ++px){
      float acc = b2[o];
      #pragma unroll
      for (int c = 0; c < 16; ++c) acc = fmaf(w2[o*16 + c], tv[px][c], acc);
      float v = lrelu(acc * prm2[o] + prm2[16 + o]);
      uint32_t bits = (uint32_t)f2bu(v);
      if (px == 0) w01 = bits;
      else if (px == 1) w01 |= bits << 16;
      else if (px == 2) w23 = bits;
      else w23 |= bits << 16;
    }
    uint2 ov; ov.x = w01; ov.y = w23;
    *(uint2*)((ushort*)p + (b * 16 + o) * HW + hw) = ov;
  }
}

// ---------------------------------------------------------------------------
// row loader for depthwise conv: 10 values (cols w0-1 .. w0+8), zero-padded.
// ---------------------------------------------------------------------------
__device__ __forceinline__ void load_row10(const ushort* __restrict__ rp, int w0, float* v){
  uint4 cc = *(const uint4*)(rp + w0);
  uint32_t l = (w0 == 0)   ? 0u : (uint32_t)rp[w0 - 1];
  uint32_t r = (w0 == 504) ? 0u : (uint32_t)rp[w0 + 8];
  v[0] = us2f(l);
  v[1] = us2f(cc.x & 0xffffu); v[2] = us2f(cc.x >> 16);
  v[3] = us2f(cc.y & 0xffffu); v[4] = us2f(cc.y >> 16);
  v[5] = us2f(cc.z & 0xffffu); v[6] = us2f(cc.z >> 16);
  v[7] = us2f(cc.w & 0xffffu); v[8] = us2f(cc.w >> 16);
  v[9] = us2f(r);
}

__device__ __forceinline__ void zero_row10(float* v){
  #pragma unroll
  for (int j = 0; j < 10; ++j) v[j] = 0.0f;
}

__device__ __forceinline__ void reduce2(float s, float q, float* __restrict__ partials){
  __shared__ float l2[2];
  int tid = threadIdx.x;
  if (tid < 2) l2[tid] = 0.0f;
  __syncthreads();
  #pragma unroll
  for (int off = 32; off >= 1; off >>= 1){
    s += __shfl_xor(s, off);
    q += __shfl_xor(q, off);
  }
  if ((tid & 63) == 0){ atomicAdd(&l2[0], s); atomicAdd(&l2[1], q); }
  __syncthreads();
  if (tid < 2) partials[blockIdx.x * 2 + tid] = l2[tid];
}

// ---------------------------------------------------------------------------
// A: conv stats of p + write c0 = conv(p) (bf16). grid 4096.
// ---------------------------------------------------------------------------
__global__ __launch_bounds__(256) void k_convstat(const bf16* __restrict__ d,
                                                  const float* __restrict__ dw,
                                                  float* __restrict__ P1,
                                                  bf16* __restrict__ cout){
  int bid = blockIdx.x;
  int plane = bid >> 7, rg = bid & 127;
  int f = plane & 15;
  int tid = threadIdx.x;
  int h  = (rg << 2) + (tid >> 6);
  int w0 = (tid & 63) << 3;
  const ushort* pl = (const ushort*)d + plane * HW;
  float wf[9];
  #pragma unroll
  for (int i = 0; i < 9; ++i) wf[i] = dw[f * 9 + i];
  float v[3][10];
  #pragma unroll
  for (int dy = 0; dy < 3; ++dy){
    int row = h + dy - 1;
    if ((unsigned)row < 512u) load_row10(pl + row * 512, w0, v[dy]);
    else zero_row10(v[dy]);
  }
  float s = 0.0f, q = 0.0f;
  uint32_t cb[4];
  #pragma unroll
  for (int k = 0; k < 8; ++k){
    float acc = 0.0f;
    #pragma unroll
    for (int dy = 0; dy < 3; ++dy)
      #pragma unroll
      for (int dx = 0; dx < 3; ++dx)
        acc = fmaf(wf[dy*3 + dx], v[dy][k + dx], acc);
    s += acc; q += acc * acc;
    uint32_t bits = (uint32_t)f2bu(acc);
    if ((k & 1) == 0) cb[k >> 1] = bits; else cb[k >> 1] |= bits << 16;
  }
  uint4 cv; cv.x = cb[0]; cv.y = cb[1]; cv.z = cb[2]; cv.w = cb[3];
  *(uint4*)((ushort*)cout + plane * HW + h * 512 + w0) = cv;
  reduce2(s, q, P1);
}

// ---------------------------------------------------------------------------
// wave-parallel channel-f sum of a [32 planes][128 rg][2] partials buffer.
// ---------------------------------------------------------------------------
__device__ __forceinline__ void chan_sum_wave(const float* __restrict__ P, int f, int lane,
                                              double& S, double& Q){
  S = 0.0; Q = 0.0;
  #pragma unroll
  for (int i = 0; i < 4; ++i){
    int e = lane + i * 64;                    // 0..255
    int blk = (((e >> 7) * 16 + f) << 7) + (e & 127);
    S += (double)P[blk * 2];
    Q += (double)P[blk * 2 + 1];
  }
  #pragma unroll
  for (int off = 32; off >= 1; off >>= 1){
    S += __shfl_xor(S, off);
    Q += __shfl_xor(Q, off);
  }
}

// ---------------------------------------------------------------------------
// FUSED loop kernel (c-carry, NO d-store). grid 4096, 256 threads.
// ---------------------------------------------------------------------------
__global__ __launch_bounds__(256) void k_bnfused(const bf16* __restrict__ cin,
                                                 const float* __restrict__ dw,
                                                 const float* __restrict__ gd,
                                                 const float* __restrict__ bd,
                                                 const float* __restrict__ P1in,
                                                 bf16* __restrict__ cout,
                                                 float* __restrict__ P2out,
                                                 float* __restrict__ P1out,
                                                 float* __restrict__ dparams,
                                                 int t, int write_c){
  __shared__ ushort strip[6][512];
  __shared__ float acc4[4];
  int bid = blockIdx.x;
  int plane = bid >> 7, rg = bid & 127;
  int f = plane & 15;
  int tid = threadIdx.x;

  double S, Q;
  chan_sum_wave(P1in, f, tid & 63, S, Q);
  float sc, sh;
  {
    double m = S / 524288.0;
    double v = Q / 524288.0 - m * m;
    sc = gd[f] / sqrtf((float)v + EPSF);
    sh = bd[f] - (float)m * sc;
  }
  if (plane < 16 && rg == 0 && tid == 0){
    dparams[512 + t * 32 + 2 * f]     = sc;
    dparams[512 + t * 32 + 2 * f + 1] = sh;
  }
  if (tid < 4) acc4[tid] = 0.0f;

  int h0 = rg << 2;
  int h  = h0 + (tid >> 6);
  int w0 = (tid & 63) << 3;
  const ushort* cpl = (const ushort*)cin + plane * HW;

  float s2 = 0.0f, q2 = 0.0f;
  {
    uint4 cv = *(const uint4*)(cpl + h * 512 + w0);
    float cf[8];
    cf[0] = us2f(cv.x & 0xffffu); cf[1] = us2f(cv.x >> 16);
    cf[2] = us2f(cv.y & 0xffffu); cf[3] = us2f(cv.y >> 16);
    cf[4] = us2f(cv.z & 0xffffu); cf[5] = us2f(cv.z >> 16);
    cf[6] = us2f(cv.w & 0xffffu); cf[7] = us2f(cv.w >> 16);
    uint32_t ob[4];
    #pragma unroll
    for (int k = 0; k < 8; ++k){
      float vv = lrelu(fmaf(cf[k], sc, sh));
      uint32_t bits = (uint32_t)f2bu(vv);
      if ((k & 1) == 0) ob[k >> 1] = bits; else ob[k >> 1] |= bits << 16;
      s2 += vv; q2 += vv * vv;
    }
    uint4 ov; ov.x = ob[0]; ov.y = ob[1]; ov.z = ob[2]; ov.w = ob[3];
    *(uint4*)&strip[1 + (tid >> 6)][w0] = ov;
  }

  if (tid < 128){
    int hh = (tid < 64) ? (h0 - 1) : (h0 + 4);
    int si = (tid < 64) ? 0 : 5;
    int wh0 = (tid & 63) << 3;
    uint4 hv; hv.x = 0; hv.y = 0; hv.z = 0; hv.w = 0;
    if ((unsigned)hh < 512u){
      uint4 cv = *(const uint4*)(cpl + hh * 512 + wh0);
      float cf[8];
      cf[0] = us2f(cv.x & 0xffffu); cf[1] = us2f(cv.x >> 16);
      cf[2] = us2f(cv.y & 0xffffu); cf[3] = us2f(cv.y >> 16);
      cf[4] = us2f(cv.z & 0xffffu); cf[5] = us2f(cv.z >> 16);
      cf[6] = us2f(cv.w & 0xffffu); cf[7] = us2f(cv.w >> 16);
      uint32_t hb[4];
      #pragma unroll
      for (int k = 0; k < 8; ++k){
        float vv = lrelu(fmaf(cf[k], sc, sh));
        uint32_t bits = (uint32_t)f2bu(vv);
        if ((k & 1) == 0) hb[k >> 1] = bits; else hb[k >> 1] |= bits << 16;
      }
      hv.x = hb[0]; hv.y = hb[1]; hv.z = hb[2]; hv.w = hb[3];
    }
    *(uint4*)&strip[si][wh0] = hv;
  }
  __syncthreads();

  float wf[9];
  #pragma unroll
  for (int i = 0; i < 9; ++i) wf[i] = dw[f * 9 + i];
  float s1 = 0.0f, q1 = 0.0f;
  {
    int si = 1 + (tid >> 6);
    float v[3][10];
    #pragma unroll
    for (int dy = 0; dy < 3; ++dy)
      load_row10(&strip[si - 1 + dy][0], w0, v[dy]);
    uint32_t cb[4];
    #pragma unroll
    for (int k = 0; k < 8; ++k){
      float acc = 0.0f;
      #pragma unroll
      for (int dy = 0; dy < 3; ++dy)
        #pragma unroll
        for (int dx = 0; dx < 3; ++dx)
          acc = fmaf(wf[dy*3 + dx], v[dy][k + dx], acc);
      s1 += acc; q1 += acc * acc;
      uint32_t bits = (uint32_t)f2bu(acc);
      if ((k & 1) == 0) cb[k >> 1] = bits; else cb[k >> 1] |= bits << 16;
    }
    if (write_c){
      uint4 cv2; cv2.x = cb[0]; cv2.y = cb[1]; cv2.z = cb[2]; cv2.w = cb[3];
      *(uint4*)((ushort*)cout + plane * HW + h * 512 + w0) = cv2;
    }
  }

  #pragma unroll
  for (int off = 32; off >= 1; off >>= 1){
    s2 += __shfl_xor(s2, off);
    q2 += __shfl_xor(q2, off);
    s1 += __shfl_xor(s1, off);
    q1 += __shfl_xor(q1, off);
  }
  if ((tid & 63) == 0){
    atomicAdd(&acc4[0], s2); atomicAdd(&acc4[1], q2);
    atomicAdd(&acc4[2], s1); atomicAdd(&acc4[3], q1);
  }
  __syncthreads();
  if (tid < 2)      P2out[bid * 2 + tid]       = acc4[tid];
  else if (tid < 4) P1out[bid * 2 + (tid - 2)] = acc4[tid];
}

// ---------------------------------------------------------------------------
// F: assemble out. 8 px/thread; prologue computes this block's f wdt/hgt
// quadruples from P2 via wave shuffles (replaces the k_fin_all launch;
// bit-identical across blocks); 12 uint4 loads up-front; d_t recomputed
// from c_t + (sc_t, sh_t).
// ---------------------------------------------------------------------------
__device__ __forceinline__ void conv8(uint4 cc, float* v){
  v[0] = us2f(cc.x & 0xffffu); v[1] = us2f(cc.x >> 16);
  v[2] = us2f(cc.y & 0xffffu); v[3] = us2f(cc.y >> 16);
  v[4] = us2f(cc.z & 0xffffu); v[5] = us2f(cc.z >> 16);
  v[6] = us2f(cc.w & 0xffffu); v[7] = us2f(cc.w >> 16);
}

__global__ __launch_bounds__(256) void k_final(const bf16* __restrict__ p,
                                               const bf16* __restrict__ c1,
                                               const bf16* __restrict__ c2,
                                               const bf16* __restrict__ c3,
                                               const bf16* __restrict__ c4,
                                               const bf16* __restrict__ c5,
                                               const float* __restrict__ P2,
                                               const float* __restrict__ ww,
                                               const float* __restrict__ gw,
                                               const float* __restrict__ bw,
                                               const float* __restrict__ wh,
                                               const float* __restrict__ gh,
                                               const float* __restrict__ bh,
                                               const float* __restrict__ dparams,
                                               float* __restrict__ out){
  int tid = threadIdx.x;
  int f = blockIdx.x >> 7;                      // 128 blocks per f
  int gid = blockIdx.x * 256 + tid;             // 0 .. 524287
  int hw = (gid & 32767) << 3;
  int fo = f * HW + hw;
  int f1 = (16 + f) * HW + hw;

  // issue all 12 loads first
  uint4 rp0 = *(const uint4*)((const ushort*)p + fo);
  uint4 rp1 = *(const uint4*)((const ushort*)p + f1);
  uint4 r0a = *(const uint4*)((const ushort*)c1 + fo);
  uint4 r0b = *(const uint4*)((const ushort*)c1 + f1);
  uint4 r1a = *(const uint4*)((const ushort*)c2 + fo);
  uint4 r1b = *(const uint4*)((const ushort*)c2 + f1);
  uint4 r2a = *(const uint4*)((const ushort*)c3 + fo);
  uint4 r2b = *(const uint4*)((const ushort*)c3 + f1);
  uint4 r3a = *(const uint4*)((const ushort*)c4 + fo);
  uint4 r3b = *(const uint4*)((const ushort*)c4 + f1);
  uint4 r4a = *(const uint4*)((const ushort*)c5 + fo);
  uint4 r4b = *(const uint4*)((const ushort*)c5 + f1);

  // prologue: wdt/hgt params for this f (wave-parallel, latency hidden by
  // the loads above; identical deterministic result in every block/wave)
  float swA[5], twA[5], shA[5], thA[5], scA[5], sbA[5];
  float wwf = ww[f], gwf = gw[f], bwf = bw[f];
  float whf = wh[f], ghf = gh[f], bhf = bh[f];
  int lane = tid & 63;
  #pragma unroll
  for (int t = 0; t < 5; ++t){
    double S, Q;
    chan_sum_wave(P2 + t * 8192, f, lane, S, Q);
    float m = (float)(S / 524288.0);
    float v = (float)(Q / 524288.0) - m * m;
    swA[t] = wwf * gwf / sqrtf(wwf * wwf * v + EPSF);
    twA[t] = bwf - m * swA[t];
    shA[t] = whf * ghf / sqrtf(whf * whf * v + EPSF);
    thA[t] = bhf - m * shA[t];
    scA[t] = dparams[512 + t * 32 + 2 * f];
    sbA[t] = dparams[512 + t * 32 + 2 * f + 1];
  }

  float pf[8], pg[8];
  conv8(rp0, pf); conv8(rp1, pg);
  float a00[8], a01[8], a10[8], a11[8];
  #pragma unroll
  for (int k = 0; k < 8; ++k){ a00[k] = pf[k]; a01[k] = pg[k]; a10[k] = pf[k]; a11[k] = pg[k]; }

  uint4 ra[5] = { r0a, r1a, r2a, r3a, r4a };
  uint4 rb[5] = { r0b, r1b, r2b, r3b, r4b };
  #pragma unroll
  for (int t = 0; t < 5; ++t){
    float cv0[8], cv1[8];
    conv8(ra[t], cv0); conv8(rb[t], cv1);
    float sw = swA[t], tw = twA[t], sh = shA[t], th = thA[t];
    float sc = scA[t], sb = sbA[t];
    #pragma unroll
    for (int k = 0; k < 8; ++k){
      float dv0 = lrelu(fmaf(cv0[k], sc, sb));
      float dv1 = lrelu(fmaf(cv1[k], sc, sb));
      a00[k] += lrelu(fmaf(dv0, sw, tw));
      a01[k] += lrelu(fmaf(dv0, sh, th));
      a10[k] += lrelu(fmaf(dv1, sw, tw));
      a11[k] += lrelu(fmaf(dv1, sh, th));
    }
  }
  #pragma unroll
  for (int half = 0; half < 2; ++half){
    float4 v0 = { a00[half*4+0], a00[half*4+1], a00[half*4+2], a00[half*4+3] };
    float4 v1 = { a01[half*4+0], a01[half*4+1], a01[half*4+2], a01[half*4+3] };
    float4 v2 = { a10[half*4+0], a10[half*4+1], a10[half*4+2], a10[half*4+3] };
    float4 v3 = { a11[half*4+0], a11[half*4+1], a11[half*4+2], a11[half*4+3] };
    *(float4*)(out + f * HW + hw + half*4)        = v0;
    *(float4*)(out + (16 + f) * HW + hw + half*4) = v1;
    *(float4*)(out + (32 + f) * HW + hw + half*4) = v2;
    *(float4*)(out + (48 + f) * HW + hw + half*4) = v3;
  }
}

// ---------------------------------------------------------------------------
extern "C" void kernel_launch(void* const* d_in, const int* in_sizes, int n_in,
                              void* d_out, int out_size, void* d_ws, size_t ws_size,
                              hipStream_t stream){
  (void)in_sizes; (void)n_in; (void)out_size;
  const float* x   = (const float*)d_in[0];
  const float* w1  = (const float*)d_in[1];
  const float* b1  = (const float*)d_in[2];
  const float* g1  = (const float*)d_in[3];
  const float* be1 = (const float*)d_in[4];
  const float* w2  = (const float*)d_in[5];
  const float* b2  = (const float*)d_in[6];
  const float* g2  = (const float*)d_in[7];
  const float* be2 = (const float*)d_in[8];
  const float* dw  = (const float*)d_in[9];
  const float* gd  = (const float*)d_in[10];
  const float* bd  = (const float*)d_in[11];
  const float* ww  = (const float*)d_in[12];
  const float* gw  = (const float*)d_in[13];
  const float* bw  = (const float*)d_in[14];
  const float* wh  = (const float*)d_in[15];
  const float* gh  = (const float*)d_in[16];
  const float* bh  = (const float*)d_in[17];
  float* out = (float*)d_out;

  char* ws = (char*)d_ws;
  size_t off = 0;
  auto alloc = [&](size_t sz) -> void* {
    void* ptr = ws + off;
    off = (off + sz + 4095) & ~(size_t)4095;
    return ptr;
  };
  uint8_t* xm    = (uint8_t*)alloc((size_t)6 * HW);
  bf16*    p     = (bf16*)   alloc((size_t)32 * HW * 2);
  bf16*    cbuf[5];
  for (int i = 0; i < 5; ++i) cbuf[i] = (bf16*)alloc((size_t)32 * HW * 2);
  float*   Pp1    = (float*)  alloc((size_t)512 * 32 * 4);
  float*   Pp2    = (float*)  alloc((size_t)512 * 32 * 4);
  float*   P1a    = (float*)  alloc((size_t)4096 * 2 * 4);
  float*   P1b    = (float*)  alloc((size_t)4096 * 2 * 4);
  float*   P2     = (float*)  alloc((size_t)5 * 4096 * 2 * 4);
  float*   dparams= (float*)  alloc(4096);
  if (ws_size < off) return;   // workspace too small: fail visibly (untouched out)

  k_mode     <<<dim3(768), dim3(256), 0, stream>>>(x, xm);
  k_stats1   <<<dim3(512), dim3(256), 0, stream>>>(xm, w1, b1, Pp1);
  k_stats2   <<<dim3(512), dim3(256), 0, stream>>>(xm, w1, b1, w2, b2,
                                                   Pp1, g1, be1, Pp2);
  k_prep     <<<dim3(512), dim3(256), 0, stream>>>(xm, w1, b1, w2, b2,
                                                   Pp1, g1, be1, Pp2, g2, be2, p);
  k_convstat <<<dim3(4096), dim3(256), 0, stream>>>(p, dw, P1a, cbuf[0]);

  float* Pin = P1a; float* Pout = P1b;
  for (int t = 0; t < 5; ++t){
    k_bnfused<<<dim3(4096), dim3(256), 0, stream>>>(
        cbuf[t], dw, gd, bd, Pin,
        (t < 4) ? cbuf[t + 1] : cbuf[0],      // dummy target when !write_c
        P2 + t * 8192, Pout, dparams, t, (t < 4) ? 1 : 0);
    float* tmp = Pin; Pin = Pout; Pout = tmp;
  }
  k_final<<<dim3(2048), dim3(256), 0, stream>>>(p, cbuf[0], cbuf[1], cbuf[2],
                                                cbuf[3], cbuf[4], P2,
                                                ww, gw, bw, wh, gh, bh,
                                                dparams, out);
}

// Round 17
// 200.955 us; speedup vs baseline: 1.1544x; 1.0692x over previous
//
#include <hip/hip_runtime.h>
#include <hip/hip_bf16.h>
#include <stdint.h>
#include <stddef.h>

#define HW 262144          // 512*512
#define EPSF 1e-5f

typedef __hip_bfloat16 bf16;

__device__ __forceinline__ float us2f(uint32_t u){
  union { uint32_t i; float f; } c; c.i = u << 16; return c.f;
}
__device__ __forceinline__ ushort f2bu(float v){
  union { bf16 h; ushort u; } c; c.h = __float2bfloat16(v); return c.u;
}
__device__ __forceinline__ float lrelu(float v){ return v > 0.0f ? v : 0.01f * v; }
__device__ __forceinline__ uint32_t umax2(uint32_t a, uint32_t b){ return a > b ? a : b; }

// ---------------------------------------------------------------------------
// K0: 11x11 mode filter with FUSED quantize+reflect-pad staging (vectorized).
// ---------------------------------------------------------------------------
__global__ __launch_bounds__(256) void k_mode(const float* __restrict__ x,
                                              uint8_t* __restrict__ xm){
  __shared__ uint8_t tile[14 * 528];
  int tid = threadIdx.x;
  int img = blockIdx.x >> 7;
  int h0  = (blockIdx.x & 127) << 2;          // first output row of block
  {
    const float* xp = x + img * HW;
    // interior: 14 rows x 128 dwords (ws = 4*g), one u32 store each
    #pragma unroll 1
    for (int idx = tid; idx < 14 * 128; idx += 256){
      int r = idx >> 7, g = idx & 127;
      int hs = h0 + r - 5; hs = hs < 0 ? -hs : hs; if (hs > 511) hs = 1022 - hs;
      int ws = g << 2;
      float4 v = *(const float4*)(xp + hs * 512 + ws);
      uint32_t b0 = (uint32_t)(uint8_t)(int)rintf((v.x * 255.0f) / 16.0f);
      uint32_t b1 = (uint32_t)(uint8_t)(int)rintf((v.y * 255.0f) / 16.0f);
      uint32_t b2 = (uint32_t)(uint8_t)(int)rintf((v.z * 255.0f) / 16.0f);
      uint32_t b3 = (uint32_t)(uint8_t)(int)rintf((v.w * 255.0f) / 16.0f);
      *(uint32_t*)&tile[r * 528 + 8 + ws] = b0 | (b1 << 8) | (b2 << 16) | (b3 << 24);
    }
    // halo: 14 rows x 10 cols (pw 0..4 and 517..521), scalar bytes
    if (tid < 140){
      int r = tid / 10, i = tid % 10;
      int pw = (i < 5) ? i : (512 + i);      // 0..4 or 517..521
      int hs = h0 + r - 5; hs = hs < 0 ? -hs : hs; if (hs > 511) hs = 1022 - hs;
      int ws = pw - 5; ws = ws < 0 ? -ws : ws; if (ws > 511) ws = 1022 - ws;
      float v = xp[hs * 512 + ws];
      tile[r * 528 + 3 + pw] = (uint8_t)(int)rintf((v * 255.0f) / 16.0f);
    }
  }
  __syncthreads();
  int r4 = tid >> 6;                          // row within block 0..3
  int w0 = (tid & 63) << 3;                   // 0..504
  const uint8_t* base = tile + r4 * 528 + 3 + w0;
  uint32_t c0 = 0, c1 = 0, c2 = 0, c3 = 0, c4 = 0;
#define HINC(q) { uint32_t inc_ = 1u << (((q) & 3u) << 3); uint32_t rr_ = (q) >> 2; \
    c0 += (rr_==0u)?inc_:0u; c1 += (rr_==1u)?inc_:0u; c2 += (rr_==2u)?inc_:0u; \
    c3 += (rr_==3u)?inc_:0u; c4 += (rr_==4u)?inc_:0u; }
#define HDEC(q) { uint32_t inc_ = 1u << (((q) & 3u) << 3); uint32_t rr_ = (q) >> 2; \
    c0 -= (rr_==0u)?inc_:0u; c1 -= (rr_==1u)?inc_:0u; c2 -= (rr_==2u)?inc_:0u; \
    c3 -= (rr_==3u)?inc_:0u; c4 -= (rr_==4u)?inc_:0u; }
  #pragma unroll 1
  for (int r = 0; r < 11; ++r){
    const uint8_t* row = base + r * 528;
    #pragma unroll
    for (int j = 0; j < 11; ++j){ uint32_t q = row[j]; HINC(q); }
  }
  uint64_t packed = 0;
  #pragma unroll 1
  for (int s = 0; s < 8; ++s){
#define KEY(reg, sh, l) (((((reg) >> (sh)) & 0xffu) << 5) | (16u - (uint32_t)(l)))
    uint32_t m0 = umax2(umax2(KEY(c0,0,0),  KEY(c0,8,1)),  umax2(KEY(c0,16,2),  KEY(c0,24,3)));
    uint32_t m1 = umax2(umax2(KEY(c1,0,4),  KEY(c1,8,5)),  umax2(KEY(c1,16,6),  KEY(c1,24,7)));
    uint32_t m2 = umax2(umax2(KEY(c2,0,8),  KEY(c2,8,9)),  umax2(KEY(c2,16,10), KEY(c2,24,11)));
    uint32_t m3 = umax2(umax2(KEY(c3,0,12), KEY(c3,8,13)), umax2(KEY(c3,16,14), KEY(c3,24,15)));
    uint32_t m  = umax2(umax2(umax2(m0, m1), umax2(m2, m3)), KEY(c4,0,16));
#undef KEY
    uint32_t lvl = 16u - (m & 31u);
    packed |= ((uint64_t)lvl) << (8 * s);
    if (s < 7){
      #pragma unroll
      for (int r = 0; r < 11; ++r){
        uint32_t qo = base[r * 528 + s];      HDEC(qo);
        uint32_t qn = base[r * 528 + s + 11]; HINC(qn);
      }
    }
  }
#undef HINC
#undef HDEC
  *(uint64_t*)(xm + img * HW + (h0 + r4) * 512 + w0) = packed;
}

// ---------------------------------------------------------------------------
// block reduction of per-thread su[16]/sq[16] -> partials[block][32]
// ---------------------------------------------------------------------------
__device__ __forceinline__ void reduce16(float* su, float* sq, float* __restrict__ partials){
  __shared__ float lsum[32];
  int tid = threadIdx.x;
  if (tid < 32) lsum[tid] = 0.0f;
  __syncthreads();
  #pragma unroll
  for (int o = 0; o < 16; ++o){
    float s = su[o], q = sq[o];
    #pragma unroll
    for (int off = 32; off >= 1; off >>= 1){
      s += __shfl_xor(s, off);
      q += __shfl_xor(q, off);
    }
    if ((tid & 63) == 0){ atomicAdd(&lsum[o], s); atomicAdd(&lsum[16 + o], q); }
  }
  __syncthreads();
  if (tid < 32) partials[blockIdx.x * 32 + tid] = lsum[tid];
}

// ---------------------------------------------------------------------------
// per-block BN-param computation from a [512][32] partials buffer.
// ---------------------------------------------------------------------------
__device__ __forceinline__ void prep_params(const float* __restrict__ Pp,
                                            const float* __restrict__ g,
                                            const float* __restrict__ bb,
                                            float* prm, float* partS, double* totS){
  int tid = threadIdx.x;
  int o = tid & 31, gg = tid >> 5;            // 8 groups x 32 outputs
  float s0 = 0.0f, s1 = 0.0f, s2 = 0.0f, s3 = 0.0f;
  #pragma unroll
  for (int j = 0; j < 64; j += 4){
    s0 += Pp[(gg * 64 + j    ) * 32 + o];
    s1 += Pp[(gg * 64 + j + 1) * 32 + o];
    s2 += Pp[(gg * 64 + j + 2) * 32 + o];
    s3 += Pp[(gg * 64 + j + 3) * 32 + o];
  }
  partS[gg * 32 + o] = (s0 + s1) + (s2 + s3);
  __syncthreads();
  if (tid < 32){
    double t = 0.0;
    #pragma unroll
    for (int k = 0; k < 8; ++k) t += (double)partS[k * 32 + tid];
    totS[tid] = t;
  }
  __syncthreads();
  if (tid < 16){
    double m = totS[tid] / 524288.0;
    double v = totS[16 + tid] / 524288.0 - m * m;
    float sc = g[tid] / sqrtf((float)v + EPSF);
    prm[tid] = sc;
    prm[16 + tid] = bb[tid] - (float)m * sc;
  }
  __syncthreads();
}

// ---------------------------------------------------------------------------
// K1: stats of p1 = conv1x1(xm). 4 px/thread. grid 512 x 256. -> Pp1
// ---------------------------------------------------------------------------
__global__ __launch_bounds__(256) void k_stats1(const uint8_t* __restrict__ xm,
                                                const float* __restrict__ w1,
                                                const float* __restrict__ b1,
                                                float* __restrict__ partials){
  int t0 = (blockIdx.x * 256 + threadIdx.x) << 2;
  int b = t0 >> 18, hw = t0 & (HW - 1);
  uint32_t q0 = *(const uint32_t*)(xm + (b * 3 + 0) * HW + hw);
  uint32_t q1 = *(const uint32_t*)(xm + (b * 3 + 1) * HW + hw);
  uint32_t q2 = *(const uint32_t*)(xm + (b * 3 + 2) * HW + hw);
  float su[16], sq[16];
  #pragma unroll
  for (int o = 0; o < 16; ++o){ su[o] = 0.0f; sq[o] = 0.0f; }
  #pragma unroll
  for (int px = 0; px < 4; ++px){
    float x0 = (float)((q0 >> (8 * px)) & 0xffu) * 0.0625f;
    float x1 = (float)((q1 >> (8 * px)) & 0xffu) * 0.0625f;
    float x2 = (float)((q2 >> (8 * px)) & 0xffu) * 0.0625f;
    #pragma unroll
    for (int o = 0; o < 16; ++o){
      float v = b1[o] + w1[o*3]*x0 + w1[o*3+1]*x1 + w1[o*3+2]*x2;
      su[o] += v; sq[o] += v * v;
    }
  }
  reduce16(su, sq, partials);
}

// ---------------------------------------------------------------------------
// K2: prologue bn1 params from Pp1; recompute p1, bn1+lrelu, p2 = conv1x1,
// stats -> Pp2.
// ---------------------------------------------------------------------------
__global__ __launch_bounds__(256) void k_stats2(const uint8_t* __restrict__ xm,
                                                const float* __restrict__ w1,
                                                const float* __restrict__ b1,
                                                const float* __restrict__ w2,
                                                const float* __restrict__ b2,
                                                const float* __restrict__ Pp1,
                                                const float* __restrict__ g1,
                                                const float* __restrict__ be1,
                                                float* __restrict__ Pp2){
  __shared__ float prm[32];
  __shared__ float partS[8 * 32];
  __shared__ double totS[32];
  prep_params(Pp1, g1, be1, prm, partS, totS);
  int t0 = (blockIdx.x * 256 + threadIdx.x) << 2;
  int b = t0 >> 18, hw = t0 & (HW - 1);
  uint32_t q0 = *(const uint32_t*)(xm + (b * 3 + 0) * HW + hw);
  uint32_t q1 = *(const uint32_t*)(xm + (b * 3 + 1) * HW + hw);
  uint32_t q2 = *(const uint32_t*)(xm + (b * 3 + 2) * HW + hw);
  float tv[4][16];
  #pragma unroll
  for (int px = 0; px < 4; ++px){
    float x0 = (float)((q0 >> (8 * px)) & 0xffu) * 0.0625f;
    float x1 = (float)((q1 >> (8 * px)) & 0xffu) * 0.0625f;
    float x2 = (float)((q2 >> (8 * px)) & 0xffu) * 0.0625f;
    #pragma unroll
    for (int o = 0; o < 16; ++o){
      float v = b1[o] + w1[o*3]*x0 + w1[o*3+1]*x1 + w1[o*3+2]*x2;
      tv[px][o] = lrelu(v * prm[o] + prm[16 + o]);
    }
  }
  float su[16], sq[16];
  #pragma unroll
  for (int o = 0; o < 16; ++o){ su[o] = 0.0f; sq[o] = 0.0f; }
  #pragma unroll
  for (int o = 0; o < 16; ++o){
    #pragma unroll
    for (int px = 0; px < 4; ++px){
      float acc = b2[o];
      #pragma unroll
      for (int c = 0; c < 16; ++c) acc = fmaf(w2[o*16 + c], tv[px][c], acc);
      su[o] += acc; sq[o] += acc * acc;
    }
  }
  reduce16(su, sq, Pp2);
}

// ---------------------------------------------------------------------------
// K3: prologue bn1 (Pp1) + bn2 (Pp2) params; recompute p2, bn2+lrelu,
// write p (bf16). 4 px/thread.
// ---------------------------------------------------------------------------
__global__ __launch_bounds__(256) void k_prep(const uint8_t* __restrict__ xm,
                                              const float* __restrict__ w1,
                                              const float* __restrict__ b1,
                                              const float* __restrict__ w2,
                                              const float* __restrict__ b2,
                                              const float* __restrict__ Pp1,
                                              const float* __restrict__ g1,
                                              const float* __restrict__ be1,
                                              const float* __restrict__ Pp2,
                                              const float* __restrict__ g2,
                                              const float* __restrict__ be2,
                                              bf16* __restrict__ p){
  __shared__ float prm1[32], prm2[32];
  __shared__ float partS[8 * 32];
  __shared__ double totS[32];
  prep_params(Pp1, g1, be1, prm1, partS, totS);
  prep_params(Pp2, g2, be2, prm2, partS, totS);
  int t0 = (blockIdx.x * 256 + threadIdx.x) << 2;
  int b = t0 >> 18, hw = t0 & (HW - 1);
  uint32_t q0 = *(const uint32_t*)(xm + (b * 3 + 0) * HW + hw);
  uint32_t q1 = *(const uint32_t*)(xm + (b * 3 + 1) * HW + hw);
  uint32_t q2 = *(const uint32_t*)(xm + (b * 3 + 2) * HW + hw);
  float tv[4][16];
  #pragma unroll
  for (int px = 0; px < 4; ++px){
    float x0 = (float)((q0 >> (8 * px)) & 0xffu) * 0.0625f;
    float x1 = (float)((q1 >> (8 * px)) & 0xffu) * 0.0625f;
    float x2 = (float)((q2 >> (8 * px)) & 0xffu) * 0.0625f;
    #pragma unroll
    for (int o = 0; o < 16; ++o){
      float v = b1[o] + w1[o*3]*x0 + w1[o*3+1]*x1 + w1[o*3+2]*x2;
      tv[px][o] = lrelu(v * prm1[o] + prm1[16 + o]);
    }
  }
  #pragma unroll
  for (int o = 0; o < 16; ++o){
    uint32_t w01 = 0, w23 = 0;
    #pragma unroll
    for (int px = 0; px < 4; ++px){
      float acc = b2[o];
      #pragma unroll
      for (int c = 0; c < 16; ++c) acc = fmaf(w2[o*16 + c], tv[px][c], acc);
      float v = lrelu(acc * prm2[o] + prm2[16 + o]);
      uint32_t bits = (uint32_t)f2bu(v);
      if (px == 0) w01 = bits;
      else if (px == 1) w01 |= bits << 16;
      else if (px == 2) w23 = bits;
      else w23 |= bits << 16;
    }
    uint2 ov; ov.x = w01; ov.y = w23;
    *(uint2*)((ushort*)p + (b * 16 + o) * HW + hw) = ov;
  }
}

// ---------------------------------------------------------------------------
// row loader for depthwise conv: 10 values (cols w0-1 .. w0+8), zero-padded.
// ---------------------------------------------------------------------------
__device__ __forceinline__ void load_row10(const ushort* __restrict__ rp, int w0, float* v){
  uint4 cc = *(const uint4*)(rp + w0);
  uint32_t l = (w0 == 0)   ? 0u : (uint32_t)rp[w0 - 1];
  uint32_t r = (w0 == 504) ? 0u : (uint32_t)rp[w0 + 8];
  v[0] = us2f(l);
  v[1] = us2f(cc.x & 0xffffu); v[2] = us2f(cc.x >> 16);
  v[3] = us2f(cc.y & 0xffffu); v[4] = us2f(cc.y >> 16);
  v[5] = us2f(cc.z & 0xffffu); v[6] = us2f(cc.z >> 16);
  v[7] = us2f(cc.w & 0xffffu); v[8] = us2f(cc.w >> 16);
  v[9] = us2f(r);
}

__device__ __forceinline__ void zero_row10(float* v){
  #pragma unroll
  for (int j = 0; j < 10; ++j) v[j] = 0.0f;
}

__device__ __forceinline__ void reduce2(float s, float q, float* __restrict__ partials){
  __shared__ float l2[2];
  int tid = threadIdx.x;
  if (tid < 2) l2[tid] = 0.0f;
  __syncthreads();
  #pragma unroll
  for (int off = 32; off >= 1; off >>= 1){
    s += __shfl_xor(s, off);
    q += __shfl_xor(q, off);
  }
  if ((tid & 63) == 0){ atomicAdd(&l2[0], s); atomicAdd(&l2[1], q); }
  __syncthreads();
  if (tid < 2) partials[blockIdx.x * 2 + tid] = l2[tid];
}

// ---------------------------------------------------------------------------
// A: conv stats of p + write c0 = conv(p) (bf16). grid 4096.
// ---------------------------------------------------------------------------
__global__ __launch_bounds__(256) void k_convstat(const bf16* __restrict__ d,
                                                  const float* __restrict__ dw,
                                                  float* __restrict__ P1,
                                                  bf16* __restrict__ cout){
  int bid = blockIdx.x;
  int plane = bid >> 7, rg = bid & 127;
  int f = plane & 15;
  int tid = threadIdx.x;
  int h  = (rg << 2) + (tid >> 6);
  int w0 = (tid & 63) << 3;
  const ushort* pl = (const ushort*)d + plane * HW;
  float wf[9];
  #pragma unroll
  for (int i = 0; i < 9; ++i) wf[i] = dw[f * 9 + i];
  float v[3][10];
  #pragma unroll
  for (int dy = 0; dy < 3; ++dy){
    int row = h + dy - 1;
    if ((unsigned)row < 512u) load_row10(pl + row * 512, w0, v[dy]);
    else zero_row10(v[dy]);
  }
  float s = 0.0f, q = 0.0f;
  uint32_t cb[4];
  #pragma unroll
  for (int k = 0; k < 8; ++k){
    float acc = 0.0f;
    #pragma unroll
    for (int dy = 0; dy < 3; ++dy)
      #pragma unroll
      for (int dx = 0; dx < 3; ++dx)
        acc = fmaf(wf[dy*3 + dx], v[dy][k + dx], acc);
    s += acc; q += acc * acc;
    uint32_t bits = (uint32_t)f2bu(acc);
    if ((k & 1) == 0) cb[k >> 1] = bits; else cb[k >> 1] |= bits << 16;
  }
  uint4 cv; cv.x = cb[0]; cv.y = cb[1]; cv.z = cb[2]; cv.w = cb[3];
  *(uint4*)((ushort*)cout + plane * HW + h * 512 + w0) = cv;
  reduce2(s, q, P1);
}

// ---------------------------------------------------------------------------
// wave-parallel channel-f sum of a [32 planes][128 rg][2] partials buffer.
// ---------------------------------------------------------------------------
__device__ __forceinline__ void chan_sum_wave(const float* __restrict__ P, int f, int lane,
                                              double& S, double& Q){
  S = 0.0; Q = 0.0;
  #pragma unroll
  for (int i = 0; i < 4; ++i){
    int e = lane + i * 64;                    // 0..255
    int blk = (((e >> 7) * 16 + f) << 7) + (e & 127);
    S += (double)P[blk * 2];
    Q += (double)P[blk * 2 + 1];
  }
  #pragma unroll
  for (int off = 32; off >= 1; off >>= 1){
    S += __shfl_xor(S, off);
    Q += __shfl_xor(Q, off);
  }
}

// ---------------------------------------------------------------------------
// FUSED loop kernel (c-carry, NO d-store). grid 4096, 256 threads.
// ---------------------------------------------------------------------------
__global__ __launch_bounds__(256) void k_bnfused(const bf16* __restrict__ cin,
                                                 const float* __restrict__ dw,
                                                 const float* __restrict__ gd,
                                                 const float* __restrict__ bd,
                                                 const float* __restrict__ P1in,
                                                 bf16* __restrict__ cout,
                                                 float* __restrict__ P2out,
                                                 float* __restrict__ P1out,
                                                 float* __restrict__ dparams,
                                                 int t, int write_c){
  __shared__ ushort strip[6][512];
  __shared__ float acc4[4];
  int bid = blockIdx.x;
  int plane = bid >> 7, rg = bid & 127;
  int f = plane & 15;
  int tid = threadIdx.x;

  double S, Q;
  chan_sum_wave(P1in, f, tid & 63, S, Q);
  float sc, sh;
  {
    double m = S / 524288.0;
    double v = Q / 524288.0 - m * m;
    sc = gd[f] / sqrtf((float)v + EPSF);
    sh = bd[f] - (float)m * sc;
  }
  if (plane < 16 && rg == 0 && tid == 0){
    dparams[512 + t * 32 + 2 * f]     = sc;
    dparams[512 + t * 32 + 2 * f + 1] = sh;
  }
  if (tid < 4) acc4[tid] = 0.0f;

  int h0 = rg << 2;
  int h  = h0 + (tid >> 6);
  int w0 = (tid & 63) << 3;
  const ushort* cpl = (const ushort*)cin + plane * HW;

  float s2 = 0.0f, q2 = 0.0f;
  {
    uint4 cv = *(const uint4*)(cpl + h * 512 + w0);
    float cf[8];
    cf[0] = us2f(cv.x & 0xffffu); cf[1] = us2f(cv.x >> 16);
    cf[2] = us2f(cv.y & 0xffffu); cf[3] = us2f(cv.y >> 16);
    cf[4] = us2f(cv.z & 0xffffu); cf[5] = us2f(cv.z >> 16);
    cf[6] = us2f(cv.w & 0xffffu); cf[7] = us2f(cv.w >> 16);
    uint32_t ob[4];
    #pragma unroll
    for (int k = 0; k < 8; ++k){
      float vv = lrelu(fmaf(cf[k], sc, sh));
      uint32_t bits = (uint32_t)f2bu(vv);
      if ((k & 1) == 0) ob[k >> 1] = bits; else ob[k >> 1] |= bits << 16;
      s2 += vv; q2 += vv * vv;
    }
    uint4 ov; ov.x = ob[0]; ov.y = ob[1]; ov.z = ob[2]; ov.w = ob[3];
    *(uint4*)&strip[1 + (tid >> 6)][w0] = ov;
  }

  if (tid < 128){
    int hh = (tid < 64) ? (h0 - 1) : (h0 + 4);
    int si = (tid < 64) ? 0 : 5;
    int wh0 = (tid & 63) << 3;
    uint4 hv; hv.x = 0; hv.y = 0; hv.z = 0; hv.w = 0;
    if ((unsigned)hh < 512u){
      uint4 cv = *(const uint4*)(cpl + hh * 512 + wh0);
      float cf[8];
      cf[0] = us2f(cv.x & 0xffffu); cf[1] = us2f(cv.x >> 16);
      cf[2] = us2f(cv.y & 0xffffu); cf[3] = us2f(cv.y >> 16);
      cf[4] = us2f(cv.z & 0xffffu); cf[5] = us2f(cv.z >> 16);
      cf[6] = us2f(cv.w & 0xffffu); cf[7] = us2f(cv.w >> 16);
      uint32_t hb[4];
      #pragma unroll
      for (int k = 0; k < 8; ++k){
        float vv = lrelu(fmaf(cf[k], sc, sh));
        uint32_t bits = (uint32_t)f2bu(vv);
        if ((k & 1) == 0) hb[k >> 1] = bits; else hb[k >> 1] |= bits << 16;
      }
      hv.x = hb[0]; hv.y = hb[1]; hv.z = hb[2]; hv.w = hb[3];
    }
    *(uint4*)&strip[si][wh0] = hv;
  }
  __syncthreads();

  float wf[9];
  #pragma unroll
  for (int i = 0; i < 9; ++i) wf[i] = dw[f * 9 + i];
  float s1 = 0.0f, q1 = 0.0f;
  {
    int si = 1 + (tid >> 6);
    float v[3][10];
    #pragma unroll
    for (int dy = 0; dy < 3; ++dy)
      load_row10(&strip[si - 1 + dy][0], w0, v[dy]);
    uint32_t cb[4];
    #pragma unroll
    for (int k = 0; k < 8; ++k){
      float acc = 0.0f;
      #pragma unroll
      for (int dy = 0; dy < 3; ++dy)
        #pragma unroll
        for (int dx = 0; dx < 3; ++dx)
          acc = fmaf(wf[dy*3 + dx], v[dy][k + dx], acc);
      s1 += acc; q1 += acc * acc;
      uint32_t bits = (uint32_t)f2bu(acc);
      if ((k & 1) == 0) cb[k >> 1] = bits; else cb[k >> 1] |= bits << 16;
    }
    if (write_c){
      uint4 cv2; cv2.x = cb[0]; cv2.y = cb[1]; cv2.z = cb[2]; cv2.w = cb[3];
      *(uint4*)((ushort*)cout + plane * HW + h * 512 + w0) = cv2;
    }
  }

  #pragma unroll
  for (int off = 32; off >= 1; off >>= 1){
    s2 += __shfl_xor(s2, off);
    q2 += __shfl_xor(q2, off);
    s1 += __shfl_xor(s1, off);
    q1 += __shfl_xor(q1, off);
  }
  if ((tid & 63) == 0){
    atomicAdd(&acc4[0], s2); atomicAdd(&acc4[1], q2);
    atomicAdd(&acc4[2], s1); atomicAdd(&acc4[3], q1);
  }
  __syncthreads();
  if (tid < 2)      P2out[bid * 2 + tid]       = acc4[tid];
  else if (tid < 4) P1out[bid * 2 + (tid - 2)] = acc4[tid];
}

// ---------------------------------------------------------------------------
// k_fin_all: 80 wdt/hgt param quadruples, one (t,f) pair per wave. grid 20.
// ---------------------------------------------------------------------------
__global__ __launch_bounds__(256) void k_fin_all(const float* __restrict__ P2,
                                                 const float* __restrict__ ww,
                                                 const float* __restrict__ gw,
                                                 const float* __restrict__ bw,
                                                 const float* __restrict__ wh,
                                                 const float* __restrict__ gh,
                                                 const float* __restrict__ bh,
                                                 float* __restrict__ dparams){
  int tid = threadIdx.x;
  int wid = tid >> 6, lane = tid & 63;
  int pair = blockIdx.x * 4 + wid;              // 0..79
  int t = pair >> 4, f = pair & 15;
  double S, Q;
  chan_sum_wave(P2 + t * 8192, f, lane, S, Q);
  if (lane == 0){
    float m = (float)(S / 524288.0);
    float v = (float)(Q / 524288.0) - m * m;
    float sw = ww[f] * gw[f] / sqrtf(ww[f] * ww[f] * v + EPSF);
    float tw = bw[f] - m * sw;
    float s2 = wh[f] * gh[f] / sqrtf(wh[f] * wh[f] * v + EPSF);
    float t2 = bh[f] - m * s2;
    dparams[t * 64 + f]      = sw;
    dparams[t * 64 + 16 + f] = tw;
    dparams[t * 64 + 32 + f] = s2;
    dparams[t * 64 + 48 + f] = t2;
  }
}

// ---------------------------------------------------------------------------
// F: assemble out. 8 px/thread; all 12 uint4 loads up-front; d_t recomputed
// on the fly from c_t and the saved (sc_t, sh_t).
// ---------------------------------------------------------------------------
__device__ __forceinline__ void conv8(uint4 cc, float* v){
  v[0] = us2f(cc.x & 0xffffu); v[1] = us2f(cc.x >> 16);
  v[2] = us2f(cc.y & 0xffffu); v[3] = us2f(cc.y >> 16);
  v[4] = us2f(cc.z & 0xffffu); v[5] = us2f(cc.z >> 16);
  v[6] = us2f(cc.w & 0xffffu); v[7] = us2f(cc.w >> 16);
}

__global__ __launch_bounds__(256) void k_final(const bf16* __restrict__ p,
                                               const bf16* __restrict__ c1,
                                               const bf16* __restrict__ c2,
                                               const bf16* __restrict__ c3,
                                               const bf16* __restrict__ c4,
                                               const bf16* __restrict__ c5,
                                               const float* __restrict__ dparams,
                                               float* __restrict__ out){
  int tid = threadIdx.x;
  int f = blockIdx.x >> 7;                      // 128 blocks per f
  int gid = blockIdx.x * 256 + tid;             // 0 .. 524287
  int hw = (gid & 32767) << 3;
  int fo = f * HW + hw;
  int f1 = (16 + f) * HW + hw;

  uint4 rp0 = *(const uint4*)((const ushort*)p + fo);
  uint4 rp1 = *(const uint4*)((const ushort*)p + f1);
  uint4 r0a = *(const uint4*)((const ushort*)c1 + fo);
  uint4 r0b = *(const uint4*)((const ushort*)c1 + f1);
  uint4 r1a = *(const uint4*)((const ushort*)c2 + fo);
  uint4 r1b = *(const uint4*)((const ushort*)c2 + f1);
  uint4 r2a = *(const uint4*)((const ushort*)c3 + fo);
  uint4 r2b = *(const uint4*)((const ushort*)c3 + f1);
  uint4 r3a = *(const uint4*)((const ushort*)c4 + fo);
  uint4 r3b = *(const uint4*)((const ushort*)c4 + f1);
  uint4 r4a = *(const uint4*)((const ushort*)c5 + fo);
  uint4 r4b = *(const uint4*)((const ushort*)c5 + f1);

  float swA[5], twA[5], shA[5], thA[5], scA[5], sbA[5];
  #pragma unroll
  for (int t = 0; t < 5; ++t){
    swA[t] = dparams[t * 64 + f];
    twA[t] = dparams[t * 64 + 16 + f];
    shA[t] = dparams[t * 64 + 32 + f];
    thA[t] = dparams[t * 64 + 48 + f];
    scA[t] = dparams[512 + t * 32 + 2 * f];
    sbA[t] = dparams[512 + t * 32 + 2 * f + 1];
  }

  float pf[8], pg[8];
  conv8(rp0, pf); conv8(rp1, pg);
  float a00[8], a01[8], a10[8], a11[8];
  #pragma unroll
  for (int k = 0; k < 8; ++k){ a00[k] = pf[k]; a01[k] = pg[k]; a10[k] = pf[k]; a11[k] = pg[k]; }

  uint4 ra[5] = { r0a, r1a, r2a, r3a, r4a };
  uint4 rb[5] = { r0b, r1b, r2b, r3b, r4b };
  #pragma unroll
  for (int t = 0; t < 5; ++t){
    float cv0[8], cv1[8];
    conv8(ra[t], cv0); conv8(rb[t], cv1);
    float sw = swA[t], tw = twA[t], sh = shA[t], th = thA[t];
    float sc = scA[t], sb = sbA[t];
    #pragma unroll
    for (int k = 0; k < 8; ++k){
      float dv0 = lrelu(fmaf(cv0[k], sc, sb));
      float dv1 = lrelu(fmaf(cv1[k], sc, sb));
      a00[k] += lrelu(fmaf(dv0, sw, tw));
      a01[k] += lrelu(fmaf(dv0, sh, th));
      a10[k] += lrelu(fmaf(dv1, sw, tw));
      a11[k] += lrelu(fmaf(dv1, sh, th));
    }
  }
  #pragma unroll
  for (int half = 0; half < 2; ++half){
    float4 v0 = { a00[half*4+0], a00[half*4+1], a00[half*4+2], a00[half*4+3] };
    float4 v1 = { a01[half*4+0], a01[half*4+1], a01[half*4+2], a01[half*4+3] };
    float4 v2 = { a10[half*4+0], a10[half*4+1], a10[half*4+2], a10[half*4+3] };
    float4 v3 = { a11[half*4+0], a11[half*4+1], a11[half*4+2], a11[half*4+3] };
    *(float4*)(out + f * HW + hw + half*4)        = v0;
    *(float4*)(out + (16 + f) * HW + hw + half*4) = v1;
    *(float4*)(out + (32 + f) * HW + hw + half*4) = v2;
    *(float4*)(out + (48 + f) * HW + hw + half*4) = v3;
  }
}

// ---------------------------------------------------------------------------
extern "C" void kernel_launch(void* const* d_in, const int* in_sizes, int n_in,
                              void* d_out, int out_size, void* d_ws, size_t ws_size,
                              hipStream_t stream){
  (void)in_sizes; (void)n_in; (void)out_size;
  const float* x   = (const float*)d_in[0];
  const float* w1  = (const float*)d_in[1];
  const float* b1  = (const float*)d_in[2];
  const float* g1  = (const float*)d_in[3];
  const float* be1 = (const float*)d_in[4];
  const float* w2  = (const float*)d_in[5];
  const float* b2  = (const float*)d_in[6];
  const float* g2  = (const float*)d_in[7];
  const float* be2 = (const float*)d_in[8];
  const float* dw  = (const float*)d_in[9];
  const float* gd  = (const float*)d_in[10];
  const float* bd  = (const float*)d_in[11];
  const float* ww  = (const float*)d_in[12];
  const float* gw  = (const float*)d_in[13];
  const float* bw  = (const float*)d_in[14];
  const float* wh  = (const float*)d_in[15];
  const float* gh  = (const float*)d_in[16];
  const float* bh  = (const float*)d_in[17];
  float* out = (float*)d_out;

  char* ws = (char*)d_ws;
  size_t off = 0;
  auto alloc = [&](size_t sz) -> void* {
    void* ptr = ws + off;
    off = (off + sz + 4095) & ~(size_t)4095;
    return ptr;
  };
  uint8_t* xm    = (uint8_t*)alloc((size_t)6 * HW);
  bf16*    p     = (bf16*)   alloc((size_t)32 * HW * 2);
  bf16*    cbuf[5];
  for (int i = 0; i < 5; ++i) cbuf[i] = (bf16*)alloc((size_t)32 * HW * 2);
  float*   Pp1    = (float*)  alloc((size_t)512 * 32 * 4);
  float*   Pp2    = (float*)  alloc((size_t)512 * 32 * 4);
  float*   P1a    = (float*)  alloc((size_t)4096 * 2 * 4);
  float*   P1b    = (float*)  alloc((size_t)4096 * 2 * 4);
  float*   P2     = (float*)  alloc((size_t)5 * 4096 * 2 * 4);
  float*   dparams= (float*)  alloc(4096);
  if (ws_size < off) return;   // workspace too small: fail visibly (untouched out)

  k_mode     <<<dim3(768), dim3(256), 0, stream>>>(x, xm);
  k_stats1   <<<dim3(512), dim3(256), 0, stream>>>(xm, w1, b1, Pp1);
  k_stats2   <<<dim3(512), dim3(256), 0, stream>>>(xm, w1, b1, w2, b2,
                                                   Pp1, g1, be1, Pp2);
  k_prep     <<<dim3(512), dim3(256), 0, stream>>>(xm, w1, b1, w2, b2,
                                                   Pp1, g1, be1, Pp2, g2, be2, p);
  k_convstat <<<dim3(4096), dim3(256), 0, stream>>>(p, dw, P1a, cbuf[0]);

  float* Pin = P1a; float* Pout = P1b;
  for (int t = 0; t < 5; ++t){
    k_bnfused<<<dim3(4096), dim3(256), 0, stream>>>(
        cbuf[t], dw, gd, bd, Pin,
        (t < 4) ? cbuf[t + 1] : cbuf[0],      // dummy target when !write_c
        P2 + t * 8192, Pout, dparams, t, (t < 4) ? 1 : 0);
    float* tmp = Pin; Pin = Pout; Pout = tmp;
  }
  k_fin_all<<<dim3(20), dim3(256), 0, stream>>>(P2, ww, gw, bw, wh, gh, bh, dparams);
  k_final<<<dim3(2048), dim3(256), 0, stream>>>(p, cbuf[0], cbuf[1], cbuf[2],
                                                cbuf[3], cbuf[4], dparams, out);
}